// Round 2
// baseline (3941.441 us; speedup 1.0000x reference)
//
#include <hip/hip_runtime.h>
#include <hip/hip_bf16.h>

using bf16 = __hip_bfloat16;
typedef unsigned short u16;
typedef unsigned int   u32;

#define B_N 2
#define CC 128
#define HH 192
#define WW 192
#define HWS (HH*WW)          // 36864
#define NPIXT (B_N*HWS)      // 73728
#define NBLKS 576            // 24*24 halo blocks per batch
#define EPSV 1e-5f

__device__ __forceinline__ float b2f(bf16 v){ return __bfloat162float(v); }
__device__ __forceinline__ bf16  f2b(float v){ return __float2bfloat16(v); }
__device__ __forceinline__ float lo16(u32 u){ union{u32 i; float f;} x; x.i = u << 16;        return x.f; }
__device__ __forceinline__ float hi16(u32 u){ union{u32 i; float f;} x; x.i = u & 0xffff0000u; return x.f; }

// ---------------------------------------------------------------------------
// Channel GEMM over pixels: out[n][choff+co][hw] = op(sum_ci W[ci*wld+co]*in[n][ci][hw])
// 128 co x 64 pixels per block, 256 threads, K=128 in chunks of 16. Weights fp32.
// ---------------------------------------------------------------------------
template<bool IN_BF16, bool OUT_BF16, bool DO_BN, bool DO_BIAS, bool DO_RELU>
__global__ __launch_bounds__(256) void gemm128_kernel(
    const void* __restrict__ inp, const float* __restrict__ Wg, int wld,
    void* __restrict__ outp, int cstride, int choff, float scale,
    const float* __restrict__ bn_g, const float* __restrict__ bn_b,
    const float* __restrict__ bn_m, const float* __restrict__ bn_v,
    const float* __restrict__ bias)
{
    __shared__ float sw[16][128];
    __shared__ float sx[16][64];
    const int tid = threadIdx.x;
    const int pixbase = blockIdx.x * 64;
    const int n   = pixbase / HWS;
    const int hwb = pixbase - n*HWS;
    float acc[8][4];
    #pragma unroll
    for (int i=0;i<8;i++)
        #pragma unroll
        for (int j=0;j<4;j++) acc[i][j]=0.f;
    const int tc = tid >> 4, tp = tid & 15;

    for (int k0 = 0; k0 < 128; k0 += 16){
        #pragma unroll
        for (int r=0;r<8;r++){
            int e = tid + r*256;                 // 0..2047
            int ci = k0 + (e>>7), co = e & 127;
            sw[e>>7][co] = Wg[ci*wld + co];
        }
        #pragma unroll
        for (int r=0;r<4;r++){
            int e = tid + r*256;                 // 0..1023
            int ci = e>>6, c = e & 63;
            size_t gi = (size_t)(n*CC + k0 + ci)*HWS + hwb + c;
            float v;
            if (IN_BF16) v = b2f(((const bf16*)inp)[gi]);
            else         v = ((const float*)inp)[gi];
            sx[ci][c] = v;
        }
        __syncthreads();
        #pragma unroll
        for (int kk=0;kk<16;kk++){
            float4 xa = *(const float4*)&sx[kk][tp*4];
            float4 w0 = *(const float4*)&sw[kk][tc*8];
            float4 w1 = *(const float4*)&sw[kk][tc*8+4];
            float wv[8] = {w0.x,w0.y,w0.z,w0.w,w1.x,w1.y,w1.z,w1.w};
            float xv[4] = {xa.x,xa.y,xa.z,xa.w};
            #pragma unroll
            for (int i=0;i<8;i++)
                #pragma unroll
                for (int j=0;j<4;j++) acc[i][j] += wv[i]*xv[j];
        }
        __syncthreads();
    }

    #pragma unroll
    for (int i=0;i<8;i++){
        int co = tc*8 + i;
        float s = scale, bb = 0.f;
        if (DO_BN){
            float sg = bn_g[co] * rsqrtf(bn_v[co] + EPSV);
            s  = sg;
            bb = bn_b[co] - bn_m[co]*sg;
        }
        if (DO_BIAS) bb += bias[co];
        #pragma unroll
        for (int j=0;j<4;j++){
            float v = acc[i][j]*s + bb;
            if (DO_RELU) v = fmaxf(v, 0.f);
            size_t oi = (size_t)(n*cstride + choff + co)*HWS + hwb + tp*4 + j;
            if (OUT_BF16) ((bf16*)outp)[oi] = f2b(v);
            else          ((float*)outp)[oi] = v;
        }
    }
}

// ---------------------------------------------------------------------------
// conv3_w (Cin,Cout,3,3) fp32 -> wt[tap=a*3+b][ci][co]
// convT(pad=1): y[h,w] += w3[ci][co][a][b] * x[h+1-a][w+1-b]
// ---------------------------------------------------------------------------
__global__ __launch_bounds__(256) void w3t_kernel(const float* __restrict__ w3, float* __restrict__ wt)
{
    int i = blockIdx.x*256 + threadIdx.x;        // 0..147455
    int tap = i >> 14; int rem = i & 16383;
    int ci = rem >> 7, co = rem & 127;
    int a = tap/3, b = tap - a*3;
    wt[i] = w3[((size_t)(ci*128 + co)*3 + a)*3 + b];
}

// ---------------------------------------------------------------------------
// conv3 transposed (pad=1) + BN3 + residual(x fp32) + ReLU -> fp32 out
// ---------------------------------------------------------------------------
__global__ __launch_bounds__(256) void conv3_kernel(
    const bf16* __restrict__ inp, const float* __restrict__ wt,
    const float* __restrict__ xin, float* __restrict__ outp,
    const float* __restrict__ g3, const float* __restrict__ b3,
    const float* __restrict__ m3, const float* __restrict__ v3)
{
    __shared__ float sw[16][128];
    __shared__ float sx[16][64];
    const int tid = threadIdx.x;
    const int pixbase = blockIdx.x * 64;
    const int n   = pixbase / HWS;
    const int hwb = pixbase - n*HWS;
    const int h = hwb / WW, wb = hwb - h*WW;   // 64-pixel tile lies in one row (192 = 3*64)
    float acc[8][4];
    #pragma unroll
    for (int i=0;i<8;i++)
        #pragma unroll
        for (int j=0;j<4;j++) acc[i][j]=0.f;
    const int tc = tid >> 4, tp = tid & 15;

    for (int tap=0; tap<9; ++tap){
        const int a = tap/3, b = tap - a*3;
        const int hs = h + 1 - a;
        if (hs < 0 || hs >= HH) continue;       // uniform per block
        const int ws0 = wb + 1 - b;
        for (int k0=0;k0<128;k0+=16){
            #pragma unroll
            for (int r=0;r<8;r++){
                int e = tid + r*256;
                sw[e>>7][e&127] = wt[tap*16384 + (k0 + (e>>7))*128 + (e&127)];
            }
            #pragma unroll
            for (int r=0;r<4;r++){
                int e = tid + r*256;
                int ci = e>>6, c = e & 63;
                int wsrc = ws0 + c;
                sx[ci][c] = (wsrc>=0 && wsrc<WW)
                          ? b2f(inp[(size_t)(n*CC + k0 + ci)*HWS + hs*WW + wsrc]) : 0.f;
            }
            __syncthreads();
            #pragma unroll
            for (int kk=0;kk<16;kk++){
                float4 xa = *(const float4*)&sx[kk][tp*4];
                float4 w0 = *(const float4*)&sw[kk][tc*8];
                float4 w1 = *(const float4*)&sw[kk][tc*8+4];
                float wv[8] = {w0.x,w0.y,w0.z,w0.w,w1.x,w1.y,w1.z,w1.w};
                float xv[4] = {xa.x,xa.y,xa.z,xa.w};
                #pragma unroll
                for (int i=0;i<8;i++)
                    #pragma unroll
                    for (int j=0;j<4;j++) acc[i][j] += wv[i]*xv[j];
            }
            __syncthreads();
        }
    }

    #pragma unroll
    for (int i=0;i<8;i++){
        int co = tc*8 + i;
        float sg = g3[co] * rsqrtf(v3[co] + EPSV);
        float bb = b3[co] - m3[co]*sg;
        #pragma unroll
        for (int j=0;j<4;j++){
            size_t idx = (size_t)(n*CC + co)*HWS + hwb + tp*4 + j;
            float val = acc[i][j]*sg + bb + xin[idx];
            outp[idx] = fmaxf(val, 0.f);
        }
    }
}

// ---------------------------------------------------------------------------
// Halo attention, one block per (batch, 8x8 block, head). 512 threads.
// thread: q = tid>>3 (0..63), jq = tid&7; j = jr*8 + jq covers 256 window slots.
// Q pre-scaled by DH^-0.5. sim = q.k + tRH[q][iw] + tRW[q][jw]; OOB -> -3e38.
// K/V staged in LDS as raw bf16 bits, rows padded to 40 ushorts (bank-clean).
// ---------------------------------------------------------------------------
__global__ __launch_bounds__(512, 4) void attn_kernel(
    const bf16* __restrict__ Qb, const u16* __restrict__ KVb,
    const float* __restrict__ relh, const float* __restrict__ relw,
    bf16* __restrict__ outp)
{
    __shared__ float sQf[64][32];     //  8192 B
    __shared__ u16   sK[256][40];     // 20480 B
    __shared__ u16   sV[256][40];     // 20480 B
    __shared__ float sRHT[32][31];    //  3968 B (transposed rel_h)
    __shared__ float sRWT[32][31];    //  3968 B
    __shared__ float tRH[64][16];     //  4096 B  [q][window-row]
    __shared__ float tRW[64][16];     //  4096 B  [q][window-col]   total 65280 B

    const int tid  = threadIdx.x;
    const int bid  = blockIdx.x;
    const int head = bid & 3;
    const int t    = bid >> 2;
    const int n    = t / NBLKS;
    const int blk  = t - n*NBLKS;
    const int bi = blk / 24, bj = blk - bi*24;
    const int row0 = bi*8 - 4, col0 = bj*8 - 4;
    const int chq = n*CC  + head*32;   // q & out channel base
    const int chk = n*256 + head*32;   // k channel base in kv buffer
    const int chv = chk + 128;         // v channel base

    for (int e = tid; e < 992; e += 512){
        int r = e >> 5, d = e & 31;
        sRHT[d][r] = relh[e];
        sRWT[d][r] = relw[e];
    }
    #pragma unroll
    for (int r4 = 0; r4 < 4; ++r4){
        int e = tid + r4*512;
        int d = e >> 6, qq = e & 63;
        int px = (bi*8 + (qq>>3))*WW + bj*8 + (qq&7);
        sQf[qq][d] = b2f(Qb[(size_t)(chq + d)*HWS + px]);
    }
    #pragma unroll
    for (int r16 = 0; r16 < 16; ++r16){
        int e = tid + r16*512;
        int d = e >> 8, wp = e & 255;
        int rr = row0 + (wp>>4), cc2 = col0 + (wp&15);
        u16 kvv = 0, vvv = 0;
        if (rr>=0 && rr<HH && cc2>=0 && cc2<WW){
            int p = rr*WW + cc2;
            kvv = KVb[(size_t)(chk + d)*HWS + p];
            vvv = KVb[(size_t)(chv + d)*HWS + p];
        }
        sK[wp][d] = kvv;
        sV[wp][d] = vvv;
    }
    __syncthreads();

    // rel-logit tables: 2048 dot-products of length 32 (2 tables x 64 q x 16 w)
    #pragma unroll
    for (int tt = 0; tt < 4; ++tt){
        int id  = tid + tt*512;
        int tb  = id >> 10;                 // uniform per tt
        int rem = id & 1023;
        int qq  = rem >> 4, ww = rem & 15;
        int bq  = tb ? (qq & 7) : (qq >> 3);
        int r   = 15 + ww - bq;             // in [8,30]
        float acc = 0.f;
        if (tb == 0){
            #pragma unroll
            for (int d = 0; d < 32; ++d) acc += sQf[qq][d] * sRHT[d][r];
            tRH[qq][ww] = acc;
        } else {
            #pragma unroll
            for (int d = 0; d < 32; ++d) acc += sQf[qq][d] * sRWT[d][r];
            tRW[qq][ww] = acc;
        }
    }
    __syncthreads();

    const int q  = tid >> 3;
    const int jq = tid & 7;
    const int qpix = (bi*8 + (q>>3))*WW + bj*8 + (q&7);

    float qreg[32];
    #pragma unroll
    for (int d4 = 0; d4 < 8; ++d4){
        float4 v = *(const float4*)&sQf[q][d4*4];
        qreg[d4*4+0]=v.x; qreg[d4*4+1]=v.y; qreg[d4*4+2]=v.z; qreg[d4*4+3]=v.w;
    }

    float pv[32];
    float mx = -3.4e38f;
    #pragma unroll
    for (int jr = 0; jr < 32; ++jr){
        int j  = jr*8 + jq;
        int iw = j >> 4, jw = j & 15;
        int rr = row0 + iw, cc2 = col0 + jw;
        float dot = 0.f;
        const uint4* kp = (const uint4*)&sK[j][0];
        #pragma unroll
        for (int c = 0; c < 4; ++c){
            uint4 u = kp[c];
            dot += qreg[c*8+0]*lo16(u.x); dot += qreg[c*8+1]*hi16(u.x);
            dot += qreg[c*8+2]*lo16(u.y); dot += qreg[c*8+3]*hi16(u.y);
            dot += qreg[c*8+4]*lo16(u.z); dot += qreg[c*8+5]*hi16(u.z);
            dot += qreg[c*8+6]*lo16(u.w); dot += qreg[c*8+7]*hi16(u.w);
        }
        bool ok = (rr>=0 && rr<HH && cc2>=0 && cc2<WW);
        float s = ok ? (tRH[q][iw] + tRW[q][jw] + dot) : -3.0e38f;
        pv[jr] = s;
        mx = fmaxf(mx, s);
    }
    mx = fmaxf(mx, __shfl_xor(mx, 1));
    mx = fmaxf(mx, __shfl_xor(mx, 2));
    mx = fmaxf(mx, __shfl_xor(mx, 4));
    float l = 0.f;
    #pragma unroll
    for (int jr = 0; jr < 32; ++jr){
        float e = __expf(pv[jr]-mx);
        pv[jr] = e; l += e;
    }
    l += __shfl_xor(l,1); l += __shfl_xor(l,2); l += __shfl_xor(l,4);
    const float inv = 1.f / l;

    float o[32];
    #pragma unroll
    for (int d = 0; d < 32; ++d) o[d] = 0.f;
    #pragma unroll
    for (int jr = 0; jr < 32; ++jr){
        int j = jr*8 + jq;
        float w = pv[jr];
        const uint4* vp = (const uint4*)&sV[j][0];
        #pragma unroll
        for (int c = 0; c < 4; ++c){
            uint4 u = vp[c];
            o[c*8+0] += w*lo16(u.x); o[c*8+1] += w*hi16(u.x);
            o[c*8+2] += w*lo16(u.y); o[c*8+3] += w*hi16(u.y);
            o[c*8+4] += w*lo16(u.z); o[c*8+5] += w*hi16(u.z);
            o[c*8+6] += w*lo16(u.w); o[c*8+7] += w*hi16(u.w);
        }
    }
    #pragma unroll
    for (int d = 0; d < 32; ++d){
        o[d] += __shfl_xor(o[d],1);
        o[d] += __shfl_xor(o[d],2);
        o[d] += __shfl_xor(o[d],4);
    }
    #pragma unroll
    for (int d = 0; d < 32; ++d){
        if ((d >> 2) == jq)                 // static reg index, predicated write
            outp[(size_t)(chq + d)*HWS + qpix] = f2b(o[d]*inv);
    }
}

// ---------------------------------------------------------------------------
extern "C" void kernel_launch(void* const* d_in, const int* in_sizes, int n_in,
                              void* d_out, int out_size, void* d_ws, size_t ws_size,
                              hipStream_t stream)
{
    (void)in_sizes; (void)n_in; (void)out_size; (void)ws_size;
    const float* x      = (const float*)d_in[0];
    const float* w1     = (const float*)d_in[1];
    const float* bn1_g  = (const float*)d_in[2];
    const float* bn1_b  = (const float*)d_in[3];
    const float* bn1_m  = (const float*)d_in[4];
    const float* bn1_v  = (const float*)d_in[5];
    const float* to_q   = (const float*)d_in[6];
    const float* to_kv  = (const float*)d_in[7];
    const float* to_ow  = (const float*)d_in[8];
    const float* to_ob  = (const float*)d_in[9];
    const float* rel_h  = (const float*)d_in[10];
    const float* rel_w  = (const float*)d_in[11];
    const float* w3     = (const float*)d_in[12];
    const float* bn3_g  = (const float*)d_in[13];
    const float* bn3_b  = (const float*)d_in[14];
    const float* bn3_m  = (const float*)d_in[15];
    const float* bn3_v  = (const float*)d_in[16];

    // workspace layout (bf16 intermediates): 57.2 MB total
    char* ws    = (char*)d_ws;
    bf16* out1  = (bf16*)(ws + 0);              // conv1 out, later REUSED as out2 (proj out)
    bf16* kv    = (bf16*)(ws + 18874368);       // k,v: [n][256][HW]
    float* w3t  = (float*)(ws + 56623104);      // 589824 B
    // d_out (fp32, 37748736 B) doubles as scratch until the final conv overwrites it:
    bf16* qbuf    = (bf16*)d_out;               // bytes [0, 18874368)
    bf16* attnout = (bf16*)d_out + 9437184;     // bytes [18874368, 37748736)
    bf16* out2    = out1;                       // out1 dead once q/k/v are built

    const float qscale = 0.17677669529663687f;  // 32^-0.5

    w3t_kernel<<<576, 256, 0, stream>>>(w3, w3t);

    // conv1 (1x1 convT) + BN1 + ReLU : fp32 in -> bf16 out1
    gemm128_kernel<false,true,true,false,true><<<1152, 256, 0, stream>>>(
        x, w1, 128, out1, 128, 0, 1.f, bn1_g, bn1_b, bn1_m, bn1_v, nullptr);

    // q (scaled) : bf16 -> bf16 (lives in d_out)
    gemm128_kernel<true,true,false,false,false><<<1152, 256, 0, stream>>>(
        out1, to_q, 128, qbuf, 128, 0, qscale, nullptr,nullptr,nullptr,nullptr,nullptr);
    // k -> kv channels [0,128)
    gemm128_kernel<true,true,false,false,false><<<1152, 256, 0, stream>>>(
        out1, to_kv, 256, kv, 256, 0, 1.f, nullptr,nullptr,nullptr,nullptr,nullptr);
    // v -> kv channels [128,256)
    gemm128_kernel<true,true,false,false,false><<<1152, 256, 0, stream>>>(
        out1, to_kv + 128, 256, kv, 256, 128, 1.f, nullptr,nullptr,nullptr,nullptr,nullptr);

    // attention -> attnout (bf16, upper half of d_out)
    attn_kernel<<<4608, 512, 0, stream>>>(qbuf, (const u16*)kv, rel_h, rel_w, attnout);

    // out projection + bias + ReLU : bf16 -> bf16 out2 (reuses out1 slot)
    gemm128_kernel<true,true,false,true,true><<<1152, 256, 0, stream>>>(
        attnout, to_ow, 128, out2, 128, 0, 1.f, nullptr,nullptr,nullptr,nullptr, to_ob);

    // conv3 (3x3 convT) + BN3 + residual + ReLU -> fp32 d_out (overwrites scratch halves)
    conv3_kernel<<<1152, 256, 0, stream>>>(out2, w3t, x, (float*)d_out,
                                           bn3_g, bn3_b, bn3_m, bn3_v);
}

// Round 3
// 2002.302 us; speedup vs baseline: 1.9685x; 1.9685x over previous
//
#include <hip/hip_runtime.h>
#include <hip/hip_bf16.h>

using bf16 = __hip_bfloat16;
typedef unsigned short u16;
typedef unsigned int   u32;

#define B_N 2
#define CC 128
#define HH 192
#define WW 192
#define HWS (HH*WW)          // 36864
#define NPIXT (B_N*HWS)      // 73728
#define NBLKS 576            // 24*24 halo blocks per batch
#define EPSV 1e-5f

__device__ __forceinline__ float b2f(bf16 v){ return __bfloat162float(v); }
__device__ __forceinline__ bf16  f2b(float v){ return __float2bfloat16(v); }
__device__ __forceinline__ float lo16(u32 u){ union{u32 i; float f;} x; x.i = u << 16;        return x.f; }
__device__ __forceinline__ float hi16(u32 u){ union{u32 i; float f;} x; x.i = u & 0xffff0000u; return x.f; }

// ---------------------------------------------------------------------------
// Channel GEMM over pixels: out[n][choff+co][hw] = op(sum_ci W[ci*wld+co]*in[n][ci][hw])
// 128 co x 64 pixels per block, 256 threads, K=128 in chunks of 16. Weights fp32.
// ---------------------------------------------------------------------------
template<bool IN_BF16, bool OUT_BF16, bool DO_BN, bool DO_BIAS, bool DO_RELU>
__global__ __launch_bounds__(256) void gemm128_kernel(
    const void* __restrict__ inp, const float* __restrict__ Wg, int wld,
    void* __restrict__ outp, int cstride, int choff, float scale,
    const float* __restrict__ bn_g, const float* __restrict__ bn_b,
    const float* __restrict__ bn_m, const float* __restrict__ bn_v,
    const float* __restrict__ bias)
{
    __shared__ float sw[16][128];
    __shared__ float sx[16][64];
    const int tid = threadIdx.x;
    const int pixbase = blockIdx.x * 64;
    const int n   = pixbase / HWS;
    const int hwb = pixbase - n*HWS;
    float acc[8][4];
    #pragma unroll
    for (int i=0;i<8;i++)
        #pragma unroll
        for (int j=0;j<4;j++) acc[i][j]=0.f;
    const int tc = tid >> 4, tp = tid & 15;

    for (int k0 = 0; k0 < 128; k0 += 16){
        #pragma unroll
        for (int r=0;r<8;r++){
            int e = tid + r*256;                 // 0..2047
            int ci = k0 + (e>>7), co = e & 127;
            sw[e>>7][co] = Wg[ci*wld + co];
        }
        #pragma unroll
        for (int r=0;r<4;r++){
            int e = tid + r*256;                 // 0..1023
            int ci = e>>6, c = e & 63;
            size_t gi = (size_t)(n*CC + k0 + ci)*HWS + hwb + c;
            float v;
            if (IN_BF16) v = b2f(((const bf16*)inp)[gi]);
            else         v = ((const float*)inp)[gi];
            sx[ci][c] = v;
        }
        __syncthreads();
        #pragma unroll
        for (int kk=0;kk<16;kk++){
            float4 xa = *(const float4*)&sx[kk][tp*4];
            float4 w0 = *(const float4*)&sw[kk][tc*8];
            float4 w1 = *(const float4*)&sw[kk][tc*8+4];
            float wv[8] = {w0.x,w0.y,w0.z,w0.w,w1.x,w1.y,w1.z,w1.w};
            float xv[4] = {xa.x,xa.y,xa.z,xa.w};
            #pragma unroll
            for (int i=0;i<8;i++)
                #pragma unroll
                for (int j=0;j<4;j++) acc[i][j] += wv[i]*xv[j];
        }
        __syncthreads();
    }

    #pragma unroll
    for (int i=0;i<8;i++){
        int co = tc*8 + i;
        float s = scale, bb = 0.f;
        if (DO_BN){
            float sg = bn_g[co] * rsqrtf(bn_v[co] + EPSV);
            s  = sg;
            bb = bn_b[co] - bn_m[co]*sg;
        }
        if (DO_BIAS) bb += bias[co];
        #pragma unroll
        for (int j=0;j<4;j++){
            float v = acc[i][j]*s + bb;
            if (DO_RELU) v = fmaxf(v, 0.f);
            size_t oi = (size_t)(n*cstride + choff + co)*HWS + hwb + tp*4 + j;
            if (OUT_BF16) ((bf16*)outp)[oi] = f2b(v);
            else          ((float*)outp)[oi] = v;
        }
    }
}

// ---------------------------------------------------------------------------
// conv3_w (Cin,Cout,3,3) fp32 -> wt[tap=a*3+b][ci][co]
// convT(pad=1): y[h,w] += w3[ci][co][a][b] * x[h+1-a][w+1-b]
// ---------------------------------------------------------------------------
__global__ __launch_bounds__(256) void w3t_kernel(const float* __restrict__ w3, float* __restrict__ wt)
{
    int i = blockIdx.x*256 + threadIdx.x;        // 0..147455
    int tap = i >> 14; int rem = i & 16383;
    int ci = rem >> 7, co = rem & 127;
    int a = tap/3, b = tap - a*3;
    wt[i] = w3[((size_t)(ci*128 + co)*3 + a)*3 + b];
}

// ---------------------------------------------------------------------------
// conv3 transposed (pad=1) + BN3 + residual(x fp32) + ReLU -> fp32 out
// ---------------------------------------------------------------------------
__global__ __launch_bounds__(256) void conv3_kernel(
    const bf16* __restrict__ inp, const float* __restrict__ wt,
    const float* __restrict__ xin, float* __restrict__ outp,
    const float* __restrict__ g3, const float* __restrict__ b3,
    const float* __restrict__ m3, const float* __restrict__ v3)
{
    __shared__ float sw[16][128];
    __shared__ float sx[16][64];
    const int tid = threadIdx.x;
    const int pixbase = blockIdx.x * 64;
    const int n   = pixbase / HWS;
    const int hwb = pixbase - n*HWS;
    const int h = hwb / WW, wb = hwb - h*WW;   // 64-pixel tile lies in one row (192 = 3*64)
    float acc[8][4];
    #pragma unroll
    for (int i=0;i<8;i++)
        #pragma unroll
        for (int j=0;j<4;j++) acc[i][j]=0.f;
    const int tc = tid >> 4, tp = tid & 15;

    for (int tap=0; tap<9; ++tap){
        const int a = tap/3, b = tap - a*3;
        const int hs = h + 1 - a;
        if (hs < 0 || hs >= HH) continue;       // uniform per block
        const int ws0 = wb + 1 - b;
        for (int k0=0;k0<128;k0+=16){
            #pragma unroll
            for (int r=0;r<8;r++){
                int e = tid + r*256;
                sw[e>>7][e&127] = wt[tap*16384 + (k0 + (e>>7))*128 + (e&127)];
            }
            #pragma unroll
            for (int r=0;r<4;r++){
                int e = tid + r*256;
                int ci = e>>6, c = e & 63;
                int wsrc = ws0 + c;
                sx[ci][c] = (wsrc>=0 && wsrc<WW)
                          ? b2f(inp[(size_t)(n*CC + k0 + ci)*HWS + hs*WW + wsrc]) : 0.f;
            }
            __syncthreads();
            #pragma unroll
            for (int kk=0;kk<16;kk++){
                float4 xa = *(const float4*)&sx[kk][tp*4];
                float4 w0 = *(const float4*)&sw[kk][tc*8];
                float4 w1 = *(const float4*)&sw[kk][tc*8+4];
                float wv[8] = {w0.x,w0.y,w0.z,w0.w,w1.x,w1.y,w1.z,w1.w};
                float xv[4] = {xa.x,xa.y,xa.z,xa.w};
                #pragma unroll
                for (int i=0;i<8;i++)
                    #pragma unroll
                    for (int j=0;j<4;j++) acc[i][j] += wv[i]*xv[j];
            }
            __syncthreads();
        }
    }

    #pragma unroll
    for (int i=0;i<8;i++){
        int co = tc*8 + i;
        float sg = g3[co] * rsqrtf(v3[co] + EPSV);
        float bb = b3[co] - m3[co]*sg;
        #pragma unroll
        for (int j=0;j<4;j++){
            size_t idx = (size_t)(n*CC + co)*HWS + hwb + tp*4 + j;
            float val = acc[i][j]*sg + bb + xin[idx];
            outp[idx] = fmaxf(val, 0.f);
        }
    }
}

// ---------------------------------------------------------------------------
// Halo attention, one block per (batch, 8x8 block, head). 512 threads.
// thread: q = tid>>3 (0..63), jq = tid&7; j = jr*8 + jq covers 256 window slots.
// Q pre-scaled by DH^-0.5. sim = q.k + tRH[q][iw] + tRW[q][jw]; OOB -> -3e38.
// K/V staged in LDS as raw bf16 bits, rows padded to 40 ushorts.
// NOTE: no min-blocks arg in launch_bounds — ",4" caps VGPRs at 64 and spills
// ~100 regs/thread to scratch (measured r2: 10.4 GB HBM traffic, 3.2 ms).
// ---------------------------------------------------------------------------
__global__ __launch_bounds__(512) void attn_kernel(
    const bf16* __restrict__ Qb, const u16* __restrict__ KVb,
    const float* __restrict__ relh, const float* __restrict__ relw,
    bf16* __restrict__ outp)
{
    __shared__ float sQf[64][32];     //  8192 B
    __shared__ u16   sK[256][40];     // 20480 B
    __shared__ u16   sV[256][40];     // 20480 B
    __shared__ float sRHT[32][31];    //  3968 B (transposed rel_h)
    __shared__ float sRWT[32][31];    //  3968 B
    __shared__ float tRH[64][16];     //  4096 B  [q][window-row]
    __shared__ float tRW[64][16];     //  4096 B  [q][window-col]   total 65280 B

    const int tid  = threadIdx.x;
    const int bid  = blockIdx.x;
    const int head = bid & 3;
    const int t    = bid >> 2;
    const int n    = t / NBLKS;
    const int blk  = t - n*NBLKS;
    const int bi = blk / 24, bj = blk - bi*24;
    const int row0 = bi*8 - 4, col0 = bj*8 - 4;
    const int chq = n*CC  + head*32;   // q & out channel base
    const int chk = n*256 + head*32;   // k channel base in kv buffer
    const int chv = chk + 128;         // v channel base

    for (int e = tid; e < 992; e += 512){
        int r = e >> 5, d = e & 31;
        sRHT[d][r] = relh[e];
        sRWT[d][r] = relw[e];
    }
    #pragma unroll
    for (int r4 = 0; r4 < 4; ++r4){
        int e = tid + r4*512;
        int d = e >> 6, qq = e & 63;
        int px = (bi*8 + (qq>>3))*WW + bj*8 + (qq&7);
        sQf[qq][d] = b2f(Qb[(size_t)(chq + d)*HWS + px]);
    }
    #pragma unroll
    for (int r16 = 0; r16 < 16; ++r16){
        int e = tid + r16*512;
        int d = e >> 8, wp = e & 255;
        int rr = row0 + (wp>>4), cc2 = col0 + (wp&15);
        u16 kvv = 0, vvv = 0;
        if (rr>=0 && rr<HH && cc2>=0 && cc2<WW){
            int p = rr*WW + cc2;
            kvv = KVb[(size_t)(chk + d)*HWS + p];
            vvv = KVb[(size_t)(chv + d)*HWS + p];
        }
        sK[wp][d] = kvv;
        sV[wp][d] = vvv;
    }
    __syncthreads();

    // rel-logit tables: 2048 dot-products of length 32 (2 tables x 64 q x 16 w)
    #pragma unroll
    for (int tt = 0; tt < 4; ++tt){
        int id  = tid + tt*512;
        int tb  = id >> 10;                 // uniform per tt
        int rem = id & 1023;
        int qq  = rem >> 4, ww = rem & 15;
        int bq  = tb ? (qq & 7) : (qq >> 3);
        int r   = 15 + ww - bq;             // in [8,30]
        float acc = 0.f;
        if (tb == 0){
            #pragma unroll
            for (int d = 0; d < 32; ++d) acc += sQf[qq][d] * sRHT[d][r];
            tRH[qq][ww] = acc;
        } else {
            #pragma unroll
            for (int d = 0; d < 32; ++d) acc += sQf[qq][d] * sRWT[d][r];
            tRW[qq][ww] = acc;
        }
    }
    __syncthreads();

    const int q  = tid >> 3;
    const int jq = tid & 7;
    const int qpix = (bi*8 + (q>>3))*WW + bj*8 + (q&7);

    float qreg[32];
    #pragma unroll
    for (int d4 = 0; d4 < 8; ++d4){
        float4 v = *(const float4*)&sQf[q][d4*4];
        qreg[d4*4+0]=v.x; qreg[d4*4+1]=v.y; qreg[d4*4+2]=v.z; qreg[d4*4+3]=v.w;
    }

    float pv[32];
    float mx = -3.4e38f;
    #pragma unroll
    for (int jr = 0; jr < 32; ++jr){
        int j  = jr*8 + jq;
        int iw = j >> 4, jw = j & 15;
        int rr = row0 + iw, cc2 = col0 + jw;
        float dot = 0.f;
        const uint4* kp = (const uint4*)&sK[j][0];
        #pragma unroll
        for (int c = 0; c < 4; ++c){
            uint4 u = kp[c];
            dot += qreg[c*8+0]*lo16(u.x); dot += qreg[c*8+1]*hi16(u.x);
            dot += qreg[c*8+2]*lo16(u.y); dot += qreg[c*8+3]*hi16(u.y);
            dot += qreg[c*8+4]*lo16(u.z); dot += qreg[c*8+5]*hi16(u.z);
            dot += qreg[c*8+6]*lo16(u.w); dot += qreg[c*8+7]*hi16(u.w);
        }
        bool ok = (rr>=0 && rr<HH && cc2>=0 && cc2<WW);
        float s = ok ? (tRH[q][iw] + tRW[q][jw] + dot) : -3.0e38f;
        pv[jr] = s;
        mx = fmaxf(mx, s);
    }
    mx = fmaxf(mx, __shfl_xor(mx, 1));
    mx = fmaxf(mx, __shfl_xor(mx, 2));
    mx = fmaxf(mx, __shfl_xor(mx, 4));
    float l = 0.f;
    #pragma unroll
    for (int jr = 0; jr < 32; ++jr){
        float e = __expf(pv[jr]-mx);
        pv[jr] = e; l += e;
    }
    l += __shfl_xor(l,1); l += __shfl_xor(l,2); l += __shfl_xor(l,4);
    const float inv = 1.f / l;

    float o[32];
    #pragma unroll
    for (int d = 0; d < 32; ++d) o[d] = 0.f;
    #pragma unroll
    for (int jr = 0; jr < 32; ++jr){
        int j = jr*8 + jq;
        float w = pv[jr];
        const uint4* vp = (const uint4*)&sV[j][0];
        #pragma unroll
        for (int c = 0; c < 4; ++c){
            uint4 u = vp[c];
            o[c*8+0] += w*lo16(u.x); o[c*8+1] += w*hi16(u.x);
            o[c*8+2] += w*lo16(u.y); o[c*8+3] += w*hi16(u.y);
            o[c*8+4] += w*lo16(u.z); o[c*8+5] += w*hi16(u.z);
            o[c*8+6] += w*lo16(u.w); o[c*8+7] += w*hi16(u.w);
        }
    }
    #pragma unroll
    for (int d = 0; d < 32; ++d){
        o[d] += __shfl_xor(o[d],1);
        o[d] += __shfl_xor(o[d],2);
        o[d] += __shfl_xor(o[d],4);
    }
    #pragma unroll
    for (int d = 0; d < 32; ++d){
        if ((d >> 2) == jq)                 // static reg index, predicated write
            outp[(size_t)(chq + d)*HWS + qpix] = f2b(o[d]*inv);
    }
}

// ---------------------------------------------------------------------------
extern "C" void kernel_launch(void* const* d_in, const int* in_sizes, int n_in,
                              void* d_out, int out_size, void* d_ws, size_t ws_size,
                              hipStream_t stream)
{
    (void)in_sizes; (void)n_in; (void)out_size; (void)ws_size;
    const float* x      = (const float*)d_in[0];
    const float* w1     = (const float*)d_in[1];
    const float* bn1_g  = (const float*)d_in[2];
    const float* bn1_b  = (const float*)d_in[3];
    const float* bn1_m  = (const float*)d_in[4];
    const float* bn1_v  = (const float*)d_in[5];
    const float* to_q   = (const float*)d_in[6];
    const float* to_kv  = (const float*)d_in[7];
    const float* to_ow  = (const float*)d_in[8];
    const float* to_ob  = (const float*)d_in[9];
    const float* rel_h  = (const float*)d_in[10];
    const float* rel_w  = (const float*)d_in[11];
    const float* w3     = (const float*)d_in[12];
    const float* bn3_g  = (const float*)d_in[13];
    const float* bn3_b  = (const float*)d_in[14];
    const float* bn3_m  = (const float*)d_in[15];
    const float* bn3_v  = (const float*)d_in[16];

    // workspace layout (bf16 intermediates): 57.2 MB total
    char* ws    = (char*)d_ws;
    bf16* out1  = (bf16*)(ws + 0);              // conv1 out, later REUSED as out2 (proj out)
    bf16* kv    = (bf16*)(ws + 18874368);       // k,v: [n][256][HW]
    float* w3t  = (float*)(ws + 56623104);      // 589824 B
    // d_out (fp32, 37748736 B) doubles as scratch until the final conv overwrites it:
    bf16* qbuf    = (bf16*)d_out;               // bytes [0, 18874368)
    bf16* attnout = (bf16*)d_out + 9437184;     // bytes [18874368, 37748736)
    bf16* out2    = out1;                       // out1 dead once q/k/v are built

    const float qscale = 0.17677669529663687f;  // 32^-0.5

    w3t_kernel<<<576, 256, 0, stream>>>(w3, w3t);

    // conv1 (1x1 convT) + BN1 + ReLU : fp32 in -> bf16 out1
    gemm128_kernel<false,true,true,false,true><<<1152, 256, 0, stream>>>(
        x, w1, 128, out1, 128, 0, 1.f, bn1_g, bn1_b, bn1_m, bn1_v, nullptr);

    // q (scaled) : bf16 -> bf16 (lives in d_out)
    gemm128_kernel<true,true,false,false,false><<<1152, 256, 0, stream>>>(
        out1, to_q, 128, qbuf, 128, 0, qscale, nullptr,nullptr,nullptr,nullptr,nullptr);
    // k -> kv channels [0,128)
    gemm128_kernel<true,true,false,false,false><<<1152, 256, 0, stream>>>(
        out1, to_kv, 256, kv, 256, 0, 1.f, nullptr,nullptr,nullptr,nullptr,nullptr);
    // v -> kv channels [128,256)
    gemm128_kernel<true,true,false,false,false><<<1152, 256, 0, stream>>>(
        out1, to_kv + 128, 256, kv, 256, 128, 1.f, nullptr,nullptr,nullptr,nullptr,nullptr);

    // attention -> attnout (bf16, upper half of d_out)
    attn_kernel<<<4608, 512, 0, stream>>>(qbuf, (const u16*)kv, rel_h, rel_w, attnout);

    // out projection + bias + ReLU : bf16 -> bf16 out2 (reuses out1 slot)
    gemm128_kernel<true,true,false,true,true><<<1152, 256, 0, stream>>>(
        attnout, to_ow, 128, out2, 128, 0, 1.f, nullptr,nullptr,nullptr,nullptr, to_ob);

    // conv3 (3x3 convT) + BN3 + residual + ReLU -> fp32 d_out (overwrites scratch halves)
    conv3_kernel<<<1152, 256, 0, stream>>>(out2, w3t, x, (float*)d_out,
                                           bn3_g, bn3_b, bn3_m, bn3_v);
}

// Round 4
// 1014.598 us; speedup vs baseline: 3.8847x; 1.9735x over previous
//
#include <hip/hip_runtime.h>
#include <hip/hip_bf16.h>

using bf16 = __hip_bfloat16;
typedef unsigned short u16;
typedef unsigned int   u32;

#define B_N 2
#define CC 128
#define HH 192
#define WW 192
#define HWS (HH*WW)          // 36864
#define NPIXT (B_N*HWS)      // 73728
#define NBLKS 576            // 24*24 halo blocks per batch
#define EPSV 1e-5f

__device__ __forceinline__ float b2f(bf16 v){ return __bfloat162float(v); }
__device__ __forceinline__ bf16  f2b(float v){ return __float2bfloat16(v); }
__device__ __forceinline__ float lo16(u32 u){ union{u32 i; float f;} x; x.i = u << 16;        return x.f; }
__device__ __forceinline__ float hi16(u32 u){ union{u32 i; float f;} x; x.i = u & 0xffff0000u; return x.f; }

// ---------------------------------------------------------------------------
// Channel GEMM over pixels: out[n][choff+co][hw] = op(sum_ci W[ci*wld+co]*in[n][ci][hw])
// 128 co x 64 pixels per block, 256 threads, K=128 in chunks of 16. Weights fp32.
// ---------------------------------------------------------------------------
template<bool IN_BF16, bool OUT_BF16, bool DO_BN, bool DO_BIAS, bool DO_RELU>
__global__ __launch_bounds__(256) void gemm128_kernel(
    const void* __restrict__ inp, const float* __restrict__ Wg, int wld,
    void* __restrict__ outp, int cstride, int choff, float scale,
    const float* __restrict__ bn_g, const float* __restrict__ bn_b,
    const float* __restrict__ bn_m, const float* __restrict__ bn_v,
    const float* __restrict__ bias)
{
    __shared__ float sw[16][128];
    __shared__ float sx[16][64];
    const int tid = threadIdx.x;
    const int pixbase = blockIdx.x * 64;
    const int n   = pixbase / HWS;
    const int hwb = pixbase - n*HWS;
    float acc[8][4];
    #pragma unroll
    for (int i=0;i<8;i++)
        #pragma unroll
        for (int j=0;j<4;j++) acc[i][j]=0.f;
    const int tc = tid >> 4, tp = tid & 15;

    for (int k0 = 0; k0 < 128; k0 += 16){
        #pragma unroll
        for (int r=0;r<8;r++){
            int e = tid + r*256;                 // 0..2047
            int ci = k0 + (e>>7), co = e & 127;
            sw[e>>7][co] = Wg[ci*wld + co];
        }
        #pragma unroll
        for (int r=0;r<4;r++){
            int e = tid + r*256;                 // 0..1023
            int ci = e>>6, c = e & 63;
            size_t gi = (size_t)(n*CC + k0 + ci)*HWS + hwb + c;
            float v;
            if (IN_BF16) v = b2f(((const bf16*)inp)[gi]);
            else         v = ((const float*)inp)[gi];
            sx[ci][c] = v;
        }
        __syncthreads();
        #pragma unroll
        for (int kk=0;kk<16;kk++){
            float4 xa = *(const float4*)&sx[kk][tp*4];
            float4 w0 = *(const float4*)&sw[kk][tc*8];
            float4 w1 = *(const float4*)&sw[kk][tc*8+4];
            float wv[8] = {w0.x,w0.y,w0.z,w0.w,w1.x,w1.y,w1.z,w1.w};
            float xv[4] = {xa.x,xa.y,xa.z,xa.w};
            #pragma unroll
            for (int i=0;i<8;i++)
                #pragma unroll
                for (int j=0;j<4;j++) acc[i][j] += wv[i]*xv[j];
        }
        __syncthreads();
    }

    #pragma unroll
    for (int i=0;i<8;i++){
        int co = tc*8 + i;
        float s = scale, bb = 0.f;
        if (DO_BN){
            float sg = bn_g[co] * rsqrtf(bn_v[co] + EPSV);
            s  = sg;
            bb = bn_b[co] - bn_m[co]*sg;
        }
        if (DO_BIAS) bb += bias[co];
        #pragma unroll
        for (int j=0;j<4;j++){
            float v = acc[i][j]*s + bb;
            if (DO_RELU) v = fmaxf(v, 0.f);
            size_t oi = (size_t)(n*cstride + choff + co)*HWS + hwb + tp*4 + j;
            if (OUT_BF16) ((bf16*)outp)[oi] = f2b(v);
            else          ((float*)outp)[oi] = v;
        }
    }
}

// ---------------------------------------------------------------------------
// conv3_w (Cin,Cout,3,3) fp32 -> wt[tap=a*3+b][ci][co]
// convT(pad=1): y[h,w] += w3[ci][co][a][b] * x[h+1-a][w+1-b]
// ---------------------------------------------------------------------------
__global__ __launch_bounds__(256) void w3t_kernel(const float* __restrict__ w3, float* __restrict__ wt)
{
    int i = blockIdx.x*256 + threadIdx.x;        // 0..147455
    int tap = i >> 14; int rem = i & 16383;
    int ci = rem >> 7, co = rem & 127;
    int a = tap/3, b = tap - a*3;
    wt[i] = w3[((size_t)(ci*128 + co)*3 + a)*3 + b];
}

// ---------------------------------------------------------------------------
// conv3 transposed (pad=1) + BN3 + residual(x fp32) + ReLU -> fp32 out
// ---------------------------------------------------------------------------
__global__ __launch_bounds__(256) void conv3_kernel(
    const bf16* __restrict__ inp, const float* __restrict__ wt,
    const float* __restrict__ xin, float* __restrict__ outp,
    const float* __restrict__ g3, const float* __restrict__ b3,
    const float* __restrict__ m3, const float* __restrict__ v3)
{
    __shared__ float sw[16][128];
    __shared__ float sx[16][64];
    const int tid = threadIdx.x;
    const int pixbase = blockIdx.x * 64;
    const int n   = pixbase / HWS;
    const int hwb = pixbase - n*HWS;
    const int h = hwb / WW, wb = hwb - h*WW;   // 64-pixel tile lies in one row (192 = 3*64)
    float acc[8][4];
    #pragma unroll
    for (int i=0;i<8;i++)
        #pragma unroll
        for (int j=0;j<4;j++) acc[i][j]=0.f;
    const int tc = tid >> 4, tp = tid & 15;

    for (int tap=0; tap<9; ++tap){
        const int a = tap/3, b = tap - a*3;
        const int hs = h + 1 - a;
        if (hs < 0 || hs >= HH) continue;       // uniform per block
        const int ws0 = wb + 1 - b;
        for (int k0=0;k0<128;k0+=16){
            #pragma unroll
            for (int r=0;r<8;r++){
                int e = tid + r*256;
                sw[e>>7][e&127] = wt[tap*16384 + (k0 + (e>>7))*128 + (e&127)];
            }
            #pragma unroll
            for (int r=0;r<4;r++){
                int e = tid + r*256;
                int ci = e>>6, c = e & 63;
                int wsrc = ws0 + c;
                sx[ci][c] = (wsrc>=0 && wsrc<WW)
                          ? b2f(inp[(size_t)(n*CC + k0 + ci)*HWS + hs*WW + wsrc]) : 0.f;
            }
            __syncthreads();
            #pragma unroll
            for (int kk=0;kk<16;kk++){
                float4 xa = *(const float4*)&sx[kk][tp*4];
                float4 w0 = *(const float4*)&sw[kk][tc*8];
                float4 w1 = *(const float4*)&sw[kk][tc*8+4];
                float wv[8] = {w0.x,w0.y,w0.z,w0.w,w1.x,w1.y,w1.z,w1.w};
                float xv[4] = {xa.x,xa.y,xa.z,xa.w};
                #pragma unroll
                for (int i=0;i<8;i++)
                    #pragma unroll
                    for (int j=0;j<4;j++) acc[i][j] += wv[i]*xv[j];
            }
            __syncthreads();
        }
    }

    #pragma unroll
    for (int i=0;i<8;i++){
        int co = tc*8 + i;
        float sg = g3[co] * rsqrtf(v3[co] + EPSV);
        float bb = b3[co] - m3[co]*sg;
        #pragma unroll
        for (int j=0;j<4;j++){
            size_t idx = (size_t)(n*CC + co)*HWS + hwb + tp*4 + j;
            float val = acc[i][j]*sg + bb + xin[idx];
            outp[idx] = fmaxf(val, 0.f);
        }
    }
}

// ---------------------------------------------------------------------------
// Halo attention, one block per (batch, 8x8 block, head). 512 threads.
// Score phase: thread (q=tid>>3, jq=tid&7) computes 32 scores (j = jr*8+jq),
// softmax over 8-lane groups, writes normalized P (bf16) to LDS.
// PV phase: thread (q=tid>>3, dg=tid&7) accumulates o[4] for d = dg*4..dg*4+3.
// P overlays score-phase-dead LDS (sQf/sK/sRHT/sRWT) -> peak regs ~100, no spill.
// NOTE: never add a min-blocks arg to launch_bounds here (",4" caps VGPR at 64
// -> 10.4 GB scratch traffic measured r2; even 128 spills ~4.2 GB, r3).
// ---------------------------------------------------------------------------
__global__ __launch_bounds__(512) void attn_kernel(
    const bf16* __restrict__ Qb, const u16* __restrict__ KVb,
    const float* __restrict__ relh, const float* __restrict__ relw,
    bf16* __restrict__ outp)
{
    // explicit LDS layout (65280 B total):
    //   [0,8192)      sQf  [64][32] f32   (dead after qreg load)
    //   [8192,28672)  sK   [256][40] u16  (dead after score phase)
    //   [28672,32640) sRHT [32][31] f32   (dead after table build)
    //   [32640,36608) sRWT [32][31] f32   (dead after table build)
    //   [0,33792)     sP   [64][264] u16  OVERLAY of the four regions above
    //   [36608,57088) sV   [256][40] u16
    //   [57088,61184) tRH  [64][16] f32
    //   [61184,65280) tRW  [64][16] f32
    __shared__ __align__(16) char smem[65280];
    float* sQf  = (float*)(smem + 0);
    u16*   sK   = (u16*)  (smem + 8192);
    float* sRHT = (float*)(smem + 28672);
    float* sRWT = (float*)(smem + 32640);
    u16*   sP   = (u16*)  (smem + 0);
    u16*   sV   = (u16*)  (smem + 36608);
    float* tRH  = (float*)(smem + 57088);
    float* tRW  = (float*)(smem + 61184);

    const int tid  = threadIdx.x;
    const int bid  = blockIdx.x;
    const int head = bid & 3;
    const int t    = bid >> 2;
    const int n    = t / NBLKS;
    const int blk  = t - n*NBLKS;
    const int bi = blk / 24, bj = blk - bi*24;
    const int row0 = bi*8 - 4, col0 = bj*8 - 4;
    const int chq = n*CC  + head*32;   // q & out channel base
    const int chk = n*256 + head*32;   // k channel base in kv buffer
    const int chv = chk + 128;         // v channel base

    for (int e = tid; e < 992; e += 512){
        int r = e >> 5, d = e & 31;
        sRHT[d*31 + r] = relh[e];
        sRWT[d*31 + r] = relw[e];
    }
    #pragma unroll
    for (int r4 = 0; r4 < 4; ++r4){
        int e = tid + r4*512;
        int d = e >> 6, qq = e & 63;
        int px = (bi*8 + (qq>>3))*WW + bj*8 + (qq&7);
        sQf[qq*32 + d] = b2f(Qb[(size_t)(chq + d)*HWS + px]);
    }
    #pragma unroll
    for (int r16 = 0; r16 < 16; ++r16){
        int e = tid + r16*512;
        int d = e >> 8, wp = e & 255;
        int rr = row0 + (wp>>4), cc2 = col0 + (wp&15);
        u16 kvv = 0, vvv = 0;
        if (rr>=0 && rr<HH && cc2>=0 && cc2<WW){
            int p = rr*WW + cc2;
            kvv = KVb[(size_t)(chk + d)*HWS + p];
            vvv = KVb[(size_t)(chv + d)*HWS + p];
        }
        sK[wp*40 + d] = kvv;
        sV[wp*40 + d] = vvv;
    }
    __syncthreads();

    // rel-logit tables: 2048 dot-products of length 32 (2 tables x 64 q x 16 w)
    #pragma unroll
    for (int tt = 0; tt < 4; ++tt){
        int id  = tid + tt*512;
        int tb  = id >> 10;                 // uniform per tt
        int rem = id & 1023;
        int qq  = rem >> 4, ww = rem & 15;
        int bq  = tb ? (qq & 7) : (qq >> 3);
        int r   = 15 + ww - bq;             // in [8,30]
        float acc = 0.f;
        if (tb == 0){
            #pragma unroll
            for (int d = 0; d < 32; ++d) acc += sQf[qq*32 + d] * sRHT[d*31 + r];
            tRH[qq*16 + ww] = acc;
        } else {
            #pragma unroll
            for (int d = 0; d < 32; ++d) acc += sQf[qq*32 + d] * sRWT[d*31 + r];
            tRW[qq*16 + ww] = acc;
        }
    }
    __syncthreads();

    const int q  = tid >> 3;
    const int jq = tid & 7;

    float qreg[32];
    #pragma unroll
    for (int d4 = 0; d4 < 8; ++d4){
        float4 v = *(const float4*)(sQf + q*32 + d4*4);
        qreg[d4*4+0]=v.x; qreg[d4*4+1]=v.y; qreg[d4*4+2]=v.z; qreg[d4*4+3]=v.w;
    }

    float pv[32];
    float mx = -3.4e38f;
    #pragma unroll
    for (int jr = 0; jr < 32; ++jr){
        int j  = jr*8 + jq;
        int iw = j >> 4, jw = j & 15;
        int rr = row0 + iw, cc2 = col0 + jw;
        float dot = 0.f;
        const uint4* kp = (const uint4*)(sK + j*40);
        #pragma unroll
        for (int c = 0; c < 4; ++c){
            uint4 u = kp[c];
            dot += qreg[c*8+0]*lo16(u.x); dot += qreg[c*8+1]*hi16(u.x);
            dot += qreg[c*8+2]*lo16(u.y); dot += qreg[c*8+3]*hi16(u.y);
            dot += qreg[c*8+4]*lo16(u.z); dot += qreg[c*8+5]*hi16(u.z);
            dot += qreg[c*8+6]*lo16(u.w); dot += qreg[c*8+7]*hi16(u.w);
        }
        bool ok = (rr>=0 && rr<HH && cc2>=0 && cc2<WW);
        float s = ok ? (tRH[q*16 + iw] + tRW[q*16 + jw] + dot) : -3.0e38f;
        pv[jr] = s;
        mx = fmaxf(mx, s);
    }
    mx = fmaxf(mx, __shfl_xor(mx, 1));
    mx = fmaxf(mx, __shfl_xor(mx, 2));
    mx = fmaxf(mx, __shfl_xor(mx, 4));
    float l = 0.f;
    #pragma unroll
    for (int jr = 0; jr < 32; ++jr){
        float e = __expf(pv[jr]-mx);
        pv[jr] = e; l += e;
    }
    l += __shfl_xor(l,1); l += __shfl_xor(l,2); l += __shfl_xor(l,4);
    const float inv = 1.f / l;

    // all reads of sK/sQf done -> safe to overlay with P after this barrier
    __syncthreads();
    #pragma unroll
    for (int jr = 0; jr < 32; ++jr){
        bf16 pb = f2b(pv[jr]*inv);
        sP[q*264 + jr*8 + jq] = *(const u16*)&pb;
    }
    __syncthreads();

    // PV phase: thread (q, dg) owns channels d0..d0+3
    const int dg = tid & 7;
    const int d0 = dg*4;
    const u16* Prow = sP + q*264;
    const u16* Vb   = sV + d0;
    float o0=0.f, o1=0.f, o2=0.f, o3=0.f;
    #pragma unroll 8
    for (int j4 = 0; j4 < 64; ++j4){
        uint2 pu = *(const uint2*)(Prow + j4*4);
        float p0=lo16(pu.x), p1=hi16(pu.x), p2=lo16(pu.y), p3=hi16(pu.y);
        const u16* vb = Vb + j4*160;       // 4 rows of 40
        uint2 v0 = *(const uint2*)(vb);
        uint2 v1 = *(const uint2*)(vb+40);
        uint2 v2 = *(const uint2*)(vb+80);
        uint2 v3 = *(const uint2*)(vb+120);
        o0 += p0*lo16(v0.x) + p1*lo16(v1.x) + p2*lo16(v2.x) + p3*lo16(v3.x);
        o1 += p0*hi16(v0.x) + p1*hi16(v1.x) + p2*hi16(v2.x) + p3*hi16(v3.x);
        o2 += p0*lo16(v0.y) + p1*lo16(v1.y) + p2*lo16(v2.y) + p3*lo16(v3.y);
        o3 += p0*hi16(v0.y) + p1*hi16(v1.y) + p2*hi16(v2.y) + p3*hi16(v3.y);
    }
    const int qpix = (bi*8 + (q>>3))*WW + bj*8 + (q&7);
    outp[(size_t)(chq + d0+0)*HWS + qpix] = f2b(o0);
    outp[(size_t)(chq + d0+1)*HWS + qpix] = f2b(o1);
    outp[(size_t)(chq + d0+2)*HWS + qpix] = f2b(o2);
    outp[(size_t)(chq + d0+3)*HWS + qpix] = f2b(o3);
}

// ---------------------------------------------------------------------------
extern "C" void kernel_launch(void* const* d_in, const int* in_sizes, int n_in,
                              void* d_out, int out_size, void* d_ws, size_t ws_size,
                              hipStream_t stream)
{
    (void)in_sizes; (void)n_in; (void)out_size; (void)ws_size;
    const float* x      = (const float*)d_in[0];
    const float* w1     = (const float*)d_in[1];
    const float* bn1_g  = (const float*)d_in[2];
    const float* bn1_b  = (const float*)d_in[3];
    const float* bn1_m  = (const float*)d_in[4];
    const float* bn1_v  = (const float*)d_in[5];
    const float* to_q   = (const float*)d_in[6];
    const float* to_kv  = (const float*)d_in[7];
    const float* to_ow  = (const float*)d_in[8];
    const float* to_ob  = (const float*)d_in[9];
    const float* rel_h  = (const float*)d_in[10];
    const float* rel_w  = (const float*)d_in[11];
    const float* w3     = (const float*)d_in[12];
    const float* bn3_g  = (const float*)d_in[13];
    const float* bn3_b  = (const float*)d_in[14];
    const float* bn3_m  = (const float*)d_in[15];
    const float* bn3_v  = (const float*)d_in[16];

    // workspace layout (bf16 intermediates): 57.2 MB total
    char* ws    = (char*)d_ws;
    bf16* out1  = (bf16*)(ws + 0);              // conv1 out, later REUSED as out2 (proj out)
    bf16* kv    = (bf16*)(ws + 18874368);       // k,v: [n][256][HW]
    float* w3t  = (float*)(ws + 56623104);      // 589824 B
    // d_out (fp32, 37748736 B) doubles as scratch until the final conv overwrites it:
    bf16* qbuf    = (bf16*)d_out;               // bytes [0, 18874368)
    bf16* attnout = (bf16*)d_out + 9437184;     // bytes [18874368, 37748736)
    bf16* out2    = out1;                       // out1 dead once q/k/v are built

    const float qscale = 0.17677669529663687f;  // 32^-0.5

    w3t_kernel<<<576, 256, 0, stream>>>(w3, w3t);

    // conv1 (1x1 convT) + BN1 + ReLU : fp32 in -> bf16 out1
    gemm128_kernel<false,true,true,false,true><<<1152, 256, 0, stream>>>(
        x, w1, 128, out1, 128, 0, 1.f, bn1_g, bn1_b, bn1_m, bn1_v, nullptr);

    // q (scaled) : bf16 -> bf16 (lives in d_out)
    gemm128_kernel<true,true,false,false,false><<<1152, 256, 0, stream>>>(
        out1, to_q, 128, qbuf, 128, 0, qscale, nullptr,nullptr,nullptr,nullptr,nullptr);
    // k -> kv channels [0,128)
    gemm128_kernel<true,true,false,false,false><<<1152, 256, 0, stream>>>(
        out1, to_kv, 256, kv, 256, 0, 1.f, nullptr,nullptr,nullptr,nullptr,nullptr);
    // v -> kv channels [128,256)
    gemm128_kernel<true,true,false,false,false><<<1152, 256, 0, stream>>>(
        out1, to_kv + 128, 256, kv, 256, 128, 1.f, nullptr,nullptr,nullptr,nullptr,nullptr);

    // attention -> attnout (bf16, upper half of d_out)
    attn_kernel<<<4608, 512, 0, stream>>>(qbuf, (const u16*)kv, rel_h, rel_w, attnout);

    // out projection + bias + ReLU : bf16 -> bf16 out2 (reuses out1 slot)
    gemm128_kernel<true,true,false,true,true><<<1152, 256, 0, stream>>>(
        attnout, to_ow, 128, out2, 128, 0, 1.f, nullptr,nullptr,nullptr,nullptr, to_ob);

    // conv3 (3x3 convT) + BN3 + residual + ReLU -> fp32 d_out (overwrites scratch halves)
    conv3_kernel<<<1152, 256, 0, stream>>>(out2, w3t, x, (float*)d_out,
                                           bn3_g, bn3_b, bn3_m, bn3_v);
}

// Round 5
// 447.701 us; speedup vs baseline: 8.8037x; 2.2662x over previous
//
#include <hip/hip_runtime.h>
#include <hip/hip_bf16.h>

using bf16 = __hip_bfloat16;
typedef unsigned short u16;
typedef unsigned int   u32;
typedef __attribute__((ext_vector_type(8))) short short8;   // 8 bf16 = 4 VGPRs (MFMA A/B frag)
typedef __attribute__((ext_vector_type(4))) float f32x4;    // MFMA C/D frag

#define B_N 2
#define CCH 128
#define HH 192
#define WW 192
#define HWS (HH*WW)          // 36864
#define NPIX (B_N*HWS)       // 73728
#define NBLKS 576            // 24*24 halo blocks per batch
#define EPSV 1e-5f
#define LDW 136              // LDS row stride (u16) for MFMA tiles: 272B, 16B-aligned, 2-way banks

__device__ __forceinline__ float b2f(bf16 v){ return __bfloat162float(v); }
__device__ __forceinline__ bf16  f2b(float v){ return __float2bfloat16(v); }
__device__ __forceinline__ float lo16(u32 u){ union{u32 i; float f;} x; x.i = u << 16;        return x.f; }
__device__ __forceinline__ float hi16(u32 u){ union{u32 i; float f;} x; x.i = u & 0xffff0000u; return x.f; }
__device__ __forceinline__ u32 pck(float a, float b){
    bf16 x = f2b(a), y = f2b(b);
    return (u32)*(u16*)&x | ((u32)*(u16*)&y << 16);
}

// ---------------------------------------------------------------------------
// x NCHW f32 -> xT [P][128] bf16  (P = n*HWS + hw, channel-contiguous rows)
// ---------------------------------------------------------------------------
__global__ __launch_bounds__(256) void transpose_in(const float* __restrict__ x,
                                                    bf16* __restrict__ xT)
{
    __shared__ float tile[128][17];
    const int t   = threadIdx.x;
    const int hw0 = blockIdx.x * 16;
    const int n   = hw0 / HWS;
    const int hwl = hw0 - n*HWS;
    const int px = t & 15, cb = t >> 4;
    #pragma unroll
    for (int r = 0; r < 8; ++r){
        int ci = r*16 + cb;
        tile[ci][px] = x[(size_t)(n*CCH + ci)*HWS + hwl + px];
    }
    __syncthreads();
    const int pix = t >> 4, cig = t & 15;
    uint4 pk;
    pk.x = pck(tile[cig*8+0][pix], tile[cig*8+1][pix]);
    pk.y = pck(tile[cig*8+2][pix], tile[cig*8+3][pix]);
    pk.z = pck(tile[cig*8+4][pix], tile[cig*8+5][pix]);
    pk.w = pck(tile[cig*8+6][pix], tile[cig*8+7][pix]);
    *(uint4*)&xT[(size_t)(hw0 + pix)*CCH + cig*8] = pk;
}

// ---------------------------------------------------------------------------
// Weight prep -> bf16 blob, all [co][ci] (ci contiguous = GEMM-K contiguous):
// [0,16K) W1 | [16K,32K) Wq*qscale | [32K,48K) Wk | [48K,64K) Wv | [64K,80K) Wo
// [80K, 224K) W3 [tap][co][ci]  (convT: y[h,w] += w3[ci][co][a][b]*x[h+1-a][w+1-b])
// ---------------------------------------------------------------------------
__global__ __launch_bounds__(256) void prep_w(
    const float* __restrict__ w1, const float* __restrict__ to_q,
    const float* __restrict__ to_kv, const float* __restrict__ to_ow,
    const float* __restrict__ w3, bf16* __restrict__ wb)
{
    int i = blockIdx.x*256 + threadIdx.x;      // < 229376
    float v;
    if (i < 16384){       int co=(i>>7)&127, ci=i&127;      v = w1[ci*128+co]; }
    else if (i < 32768){  int r=i-16384; int co=r>>7, ci=r&127; v = to_q[ci*128+co]*0.17677669529663687f; }
    else if (i < 49152){  int r=i-32768; int co=r>>7, ci=r&127; v = to_kv[ci*256+co]; }
    else if (i < 65536){  int r=i-49152; int co=r>>7, ci=r&127; v = to_kv[ci*256+128+co]; }
    else if (i < 81920){  int r=i-65536; int co=r>>7, ci=r&127; v = to_ow[ci*128+co]; }
    else { int r=i-81920; int tap=r>>14, co=(r>>7)&127, ci=r&127; int a=tap/3, b=tap-a*3;
           v = w3[((size_t)(ci*128+co)*3+a)*3+b]; }
    wb[i] = f2b(v);
}

// ---------------------------------------------------------------------------
// MFMA channel GEMM: out[pix][choff+co] = op(sum_ci inp[pix][ci]*W[co][ci])
// Tile 64 pix x 128 co, 256 thr (4 waves, wave w owns co slice w*32).
// m = pix (A = X), n = co (B = W). A/B frags use identical contiguous k-map
// (k-permutation invariance => correct for any HW k-order).
// ---------------------------------------------------------------------------
template<bool DO_BN, bool DO_BIAS, bool DO_RELU>
__global__ __launch_bounds__(256) void gemm_mfma(
    const bf16* __restrict__ inp, const bf16* __restrict__ Wp,
    bf16* __restrict__ outp, int cstride, int choff,
    const float* __restrict__ bn_g, const float* __restrict__ bn_b,
    const float* __restrict__ bn_m, const float* __restrict__ bn_v,
    const float* __restrict__ bias)
{
    __shared__ u16 sW[128*LDW];
    __shared__ u16 sX[64*LDW];
    const int tid  = threadIdx.x;
    const int pix0 = blockIdx.x * 64;
    const int lane = tid & 63;
    const int ln = lane & 15, g = lane >> 4;
    const int cow = (tid >> 6) * 32;

    #pragma unroll
    for (int r = 0; r < 8; ++r){
        int e = tid + r*256; int row = e>>4, grp = e&15;
        *(uint4*)&sW[row*LDW + grp*8] = *(const uint4*)&Wp[row*128 + grp*8];
    }
    #pragma unroll
    for (int r = 0; r < 4; ++r){
        int e = tid + r*256; int row = e>>4, grp = e&15;
        *(uint4*)&sX[row*LDW + grp*8] = *(const uint4*)&inp[(size_t)(pix0+row)*CCH + grp*8];
    }
    __syncthreads();

    f32x4 acc[4][2];
    #pragma unroll
    for (int mi=0;mi<4;mi++)
        #pragma unroll
        for (int ni=0;ni<2;ni++) acc[mi][ni] = (f32x4){0.f,0.f,0.f,0.f};

    #pragma unroll
    for (int kk = 0; kk < 4; ++kk){
        short8 fa[4], fb[2];
        #pragma unroll
        for (int mi=0;mi<4;mi++)
            fa[mi] = *(const short8*)&sX[(mi*16+ln)*LDW + kk*32 + g*8];
        #pragma unroll
        for (int ni=0;ni<2;ni++)
            fb[ni] = *(const short8*)&sW[(cow+ni*16+ln)*LDW + kk*32 + g*8];
        #pragma unroll
        for (int mi=0;mi<4;mi++)
            #pragma unroll
            for (int ni=0;ni<2;ni++)
                acc[mi][ni] = __builtin_amdgcn_mfma_f32_16x16x32_bf16(fa[mi], fb[ni], acc[mi][ni], 0, 0, 0);
    }

    float sc[2], bb[2];
    #pragma unroll
    for (int ni=0;ni<2;ni++){
        int co = cow + ni*16 + ln;
        sc[ni] = 1.f; bb[ni] = 0.f;
        if (DO_BN){ float sg = bn_g[co]*rsqrtf(bn_v[co]+EPSV); sc[ni]=sg; bb[ni]=bn_b[co]-bn_m[co]*sg; }
        if (DO_BIAS) bb[ni] += bias[co];
    }
    #pragma unroll
    for (int mi=0;mi<4;mi++)
        #pragma unroll
        for (int ni=0;ni<2;ni++)
            #pragma unroll
            for (int j=0;j<4;j++){
                int pix = pix0 + mi*16 + g*4 + j;
                int co  = cow + ni*16 + ln;
                float v = acc[mi][ni][j]*sc[ni] + bb[ni];
                if (DO_RELU) v = fmaxf(v, 0.f);
                outp[(size_t)pix*cstride + choff + co] = f2b(v);
            }
}

// ---------------------------------------------------------------------------
// conv3 transposed (pad=1) via 9-tap MFMA GEMM + BN3 + residual + ReLU.
// m = co (A = W3[tap]), n = pix (B = shifted X rows). acc persists over taps.
// Output NCHW f32 (coalesced 64B segments), input [P][128] bf16.
// ---------------------------------------------------------------------------
__global__ __launch_bounds__(256) void conv3_mfma(
    const bf16* __restrict__ inp, const bf16* __restrict__ W3p,
    const float* __restrict__ xin, float* __restrict__ outp,
    const float* __restrict__ g3, const float* __restrict__ b3,
    const float* __restrict__ m3, const float* __restrict__ v3)
{
    __shared__ u16 sW[128*LDW];
    __shared__ u16 sX[64*LDW];
    const int tid = threadIdx.x;
    const int P0  = blockIdx.x * 64;
    const int n   = P0 / HWS;
    const int hwb = P0 - n*HWS;
    const int h = hwb / WW, wb = hwb - h*WW;   // 64-pix tile within one row (64|192)
    const int lane = tid & 63, ln = lane & 15, g = lane >> 4;
    const int cow = (tid >> 6) * 32;

    f32x4 acc[2][4];
    #pragma unroll
    for (int mi=0;mi<2;mi++)
        #pragma unroll
        for (int ni=0;ni<4;ni++) acc[mi][ni] = (f32x4){0.f,0.f,0.f,0.f};

    for (int tap = 0; tap < 9; ++tap){
        const int a = tap/3, b = tap - a*3;
        const int hs = h + 1 - a;
        if (hs < 0 || hs >= HH) continue;      // uniform per block
        const int ws0 = wb + 1 - b;
        __syncthreads();                       // protect prior-tap reads
        #pragma unroll
        for (int r = 0; r < 8; ++r){
            int e = tid + r*256; int row = e>>4, grp = e&15;
            *(uint4*)&sW[row*LDW + grp*8] = *(const uint4*)&W3p[tap*16384 + row*128 + grp*8];
        }
        #pragma unroll
        for (int r = 0; r < 4; ++r){
            int e = tid + r*256; int row = e>>4, grp = e&15;
            int wsrc = ws0 + row;
            uint4 val = {0u,0u,0u,0u};
            if (wsrc >= 0 && wsrc < WW)
                val = *(const uint4*)&inp[(size_t)(n*HWS + hs*WW + wsrc)*CCH + grp*8];
            *(uint4*)&sX[row*LDW + grp*8] = val;
        }
        __syncthreads();
        #pragma unroll
        for (int kk = 0; kk < 4; ++kk){
            short8 fa[2], fb[4];
            #pragma unroll
            for (int mi=0;mi<2;mi++)
                fa[mi] = *(const short8*)&sW[(cow+mi*16+ln)*LDW + kk*32 + g*8];
            #pragma unroll
            for (int ni=0;ni<4;ni++)
                fb[ni] = *(const short8*)&sX[(ni*16+ln)*LDW + kk*32 + g*8];
            #pragma unroll
            for (int mi=0;mi<2;mi++)
                #pragma unroll
                for (int ni=0;ni<4;ni++)
                    acc[mi][ni] = __builtin_amdgcn_mfma_f32_16x16x32_bf16(fa[mi], fb[ni], acc[mi][ni], 0, 0, 0);
        }
    }

    #pragma unroll
    for (int mi=0;mi<2;mi++)
        #pragma unroll
        for (int j=0;j<4;j++){
            int co = cow + mi*16 + g*4 + j;
            float sg = g3[co]*rsqrtf(v3[co]+EPSV);
            float bc = b3[co] - m3[co]*sg;
            #pragma unroll
            for (int ni=0;ni<4;ni++){
                int pixl = hwb + ni*16 + ln;
                size_t idx = (size_t)(n*CCH + co)*HWS + pixl;
                float v = acc[mi][ni][j]*sg + bc + xin[idx];
                outp[idx] = fmaxf(v, 0.f);
            }
        }
}

// ---------------------------------------------------------------------------
// Halo attention, one block per (batch, 8x8 block, head). 512 threads.
// [pix][ch] layouts: Q [P][128], KV [P][256], out [P][128]. Internals = r4
// (LDS-P overlay, no spills). NOTE: never add min-blocks to launch_bounds
// (",4" caps VGPR at 64 -> 10.4 GB scratch traffic, measured r2).
// ---------------------------------------------------------------------------
__global__ __launch_bounds__(512) void attn_kernel(
    const bf16* __restrict__ Qb, const u16* __restrict__ KVb,
    const float* __restrict__ relh, const float* __restrict__ relw,
    bf16* __restrict__ outp)
{
    __shared__ __align__(16) char smem[65280];
    float* sQf  = (float*)(smem + 0);        // [64][32]
    u16*   sK   = (u16*)  (smem + 8192);     // [256][40]
    float* sRHT = (float*)(smem + 28672);    // [32][31]
    float* sRWT = (float*)(smem + 32640);    // [32][31]
    u16*   sP   = (u16*)  (smem + 0);        // [64][264] overlay (score-dead regions)
    u16*   sV   = (u16*)  (smem + 36608);    // [256][40]
    float* tRH  = (float*)(smem + 57088);    // [64][16]
    float* tRW  = (float*)(smem + 61184);    // [64][16]

    const int tid  = threadIdx.x;
    const int bid  = blockIdx.x;
    const int head = bid & 3;
    const int t    = bid >> 2;
    const int n    = t / NBLKS;
    const int blk  = t - n*NBLKS;
    const int bi = blk / 24, bj = blk - bi*24;
    const int row0 = bi*8 - 4, col0 = bj*8 - 4;
    const int ch0 = head*32;

    for (int e = tid; e < 992; e += 512){
        int r = e >> 5, d = e & 31;
        sRHT[d*31 + r] = relh[e];
        sRWT[d*31 + r] = relw[e];
    }
    #pragma unroll
    for (int r4i = 0; r4i < 4; ++r4i){
        int e = tid + r4i*512;
        int qq = e >> 5, d = e & 31;
        size_t P = (size_t)n*HWS + (bi*8 + (qq>>3))*WW + bj*8 + (qq&7);
        sQf[qq*32 + d] = b2f(Qb[P*CCH + ch0 + d]);
    }
    #pragma unroll
    for (int r16 = 0; r16 < 16; ++r16){
        int e = tid + r16*512;
        int wp = e >> 5, d = e & 31;
        int rr = row0 + (wp>>4), cc2 = col0 + (wp&15);
        u16 kvv = 0, vvv = 0;
        if (rr>=0 && rr<HH && cc2>=0 && cc2<WW){
            size_t P = (size_t)n*HWS + rr*WW + cc2;
            kvv = KVb[P*256 + ch0 + d];
            vvv = KVb[P*256 + 128 + ch0 + d];
        }
        sK[wp*40 + d] = kvv;
        sV[wp*40 + d] = vvv;
    }
    __syncthreads();

    #pragma unroll
    for (int tt = 0; tt < 4; ++tt){
        int id  = tid + tt*512;
        int tb  = id >> 10;
        int rem = id & 1023;
        int qq  = rem >> 4, ww = rem & 15;
        int bq  = tb ? (qq & 7) : (qq >> 3);
        int r   = 15 + ww - bq;
        float acc = 0.f;
        if (tb == 0){
            #pragma unroll
            for (int d = 0; d < 32; ++d) acc += sQf[qq*32 + d] * sRHT[d*31 + r];
            tRH[qq*16 + ww] = acc;
        } else {
            #pragma unroll
            for (int d = 0; d < 32; ++d) acc += sQf[qq*32 + d] * sRWT[d*31 + r];
            tRW[qq*16 + ww] = acc;
        }
    }
    __syncthreads();

    const int q  = tid >> 3;
    const int jq = tid & 7;

    float qreg[32];
    #pragma unroll
    for (int d4 = 0; d4 < 8; ++d4){
        float4 v = *(const float4*)(sQf + q*32 + d4*4);
        qreg[d4*4+0]=v.x; qreg[d4*4+1]=v.y; qreg[d4*4+2]=v.z; qreg[d4*4+3]=v.w;
    }

    float pv[32];
    float mx = -3.4e38f;
    #pragma unroll
    for (int jr = 0; jr < 32; ++jr){
        int j  = jr*8 + jq;
        int iw = j >> 4, jw = j & 15;
        int rr = row0 + iw, cc2 = col0 + jw;
        float dot = 0.f;
        const uint4* kp = (const uint4*)(sK + j*40);
        #pragma unroll
        for (int c = 0; c < 4; ++c){
            uint4 u = kp[c];
            dot += qreg[c*8+0]*lo16(u.x); dot += qreg[c*8+1]*hi16(u.x);
            dot += qreg[c*8+2]*lo16(u.y); dot += qreg[c*8+3]*hi16(u.y);
            dot += qreg[c*8+4]*lo16(u.z); dot += qreg[c*8+5]*hi16(u.z);
            dot += qreg[c*8+6]*lo16(u.w); dot += qreg[c*8+7]*hi16(u.w);
        }
        bool ok = (rr>=0 && rr<HH && cc2>=0 && cc2<WW);
        float s = ok ? (tRH[q*16 + iw] + tRW[q*16 + jw] + dot) : -3.0e38f;
        pv[jr] = s;
        mx = fmaxf(mx, s);
    }
    mx = fmaxf(mx, __shfl_xor(mx, 1));
    mx = fmaxf(mx, __shfl_xor(mx, 2));
    mx = fmaxf(mx, __shfl_xor(mx, 4));
    float l = 0.f;
    #pragma unroll
    for (int jr = 0; jr < 32; ++jr){
        float e = __expf(pv[jr]-mx);
        pv[jr] = e; l += e;
    }
    l += __shfl_xor(l,1); l += __shfl_xor(l,2); l += __shfl_xor(l,4);
    const float inv = 1.f / l;

    __syncthreads();
    #pragma unroll
    for (int jr = 0; jr < 32; ++jr){
        bf16 pb = f2b(pv[jr]*inv);
        sP[q*264 + jr*8 + jq] = *(const u16*)&pb;
    }
    __syncthreads();

    const int dg = tid & 7;
    const int d0 = dg*4;
    const u16* Prow = sP + q*264;
    const u16* Vb   = sV + d0;
    float o0=0.f, o1=0.f, o2=0.f, o3=0.f;
    #pragma unroll 8
    for (int j4 = 0; j4 < 64; ++j4){
        uint2 pu = *(const uint2*)(Prow + j4*4);
        float p0=lo16(pu.x), p1=hi16(pu.x), p2=lo16(pu.y), p3=hi16(pu.y);
        const u16* vb = Vb + j4*160;
        uint2 v0 = *(const uint2*)(vb);
        uint2 v1 = *(const uint2*)(vb+40);
        uint2 v2 = *(const uint2*)(vb+80);
        uint2 v3 = *(const uint2*)(vb+120);
        o0 += p0*lo16(v0.x) + p1*lo16(v1.x) + p2*lo16(v2.x) + p3*lo16(v3.x);
        o1 += p0*hi16(v0.x) + p1*hi16(v1.x) + p2*hi16(v2.x) + p3*hi16(v3.x);
        o2 += p0*lo16(v0.y) + p1*lo16(v1.y) + p2*lo16(v2.y) + p3*lo16(v3.y);
        o3 += p0*hi16(v0.y) + p1*hi16(v1.y) + p2*hi16(v2.y) + p3*hi16(v3.y);
    }
    size_t qP = (size_t)n*HWS + (bi*8 + (q>>3))*WW + bj*8 + (q&7);
    uint2 ov; ov.x = pck(o0, o1); ov.y = pck(o2, o3);
    *(uint2*)&outp[qP*CCH + ch0 + d0] = ov;
}

// ---------------------------------------------------------------------------
extern "C" void kernel_launch(void* const* d_in, const int* in_sizes, int n_in,
                              void* d_out, int out_size, void* d_ws, size_t ws_size,
                              hipStream_t stream)
{
    (void)in_sizes; (void)n_in; (void)out_size; (void)ws_size;
    const float* x      = (const float*)d_in[0];
    const float* w1     = (const float*)d_in[1];
    const float* bn1_g  = (const float*)d_in[2];
    const float* bn1_b  = (const float*)d_in[3];
    const float* bn1_m  = (const float*)d_in[4];
    const float* bn1_v  = (const float*)d_in[5];
    const float* to_q   = (const float*)d_in[6];
    const float* to_kv  = (const float*)d_in[7];
    const float* to_ow  = (const float*)d_in[8];
    const float* to_ob  = (const float*)d_in[9];
    const float* rel_h  = (const float*)d_in[10];
    const float* rel_w  = (const float*)d_in[11];
    const float* w3     = (const float*)d_in[12];
    const float* bn3_g  = (const float*)d_in[13];
    const float* bn3_b  = (const float*)d_in[14];
    const float* bn3_m  = (const float*)d_in[15];
    const float* bn3_v  = (const float*)d_in[16];

    // ws layout (76 MB; harness ws_size >= 114 MB proven in r2):
    char* ws   = (char*)d_ws;
    bf16* out1 = (bf16*)(ws + 0);              // [P][128] conv1 out; later reused as out2
    bf16* kv   = (bf16*)(ws + 18874368);       // [P][256] k|v
    bf16* xT   = (bf16*)(ws + 56623104);       // [P][128] transposed input
    bf16* wb   = (bf16*)(ws + 75497472);       // weight blob (458752 B)
    bf16* Wp1 = wb;            bf16* Wq = wb + 16384;  bf16* Wk = wb + 32768;
    bf16* Wv  = wb + 49152;    bf16* Wo = wb + 65536;  bf16* W3p = wb + 81920;
    // d_out doubles as scratch until conv3 overwrites it:
    bf16* qbuf    = (bf16*)d_out;              // [P][128]
    bf16* attnout = (bf16*)d_out + 9437184;    // [P][128]
    bf16* out2    = out1;

    transpose_in<<<4608, 256, 0, stream>>>(x, xT);
    prep_w<<<896, 256, 0, stream>>>(w1, to_q, to_kv, to_ow, w3, wb);

    // conv1 (1x1) + BN1 + ReLU
    gemm_mfma<true,false,true><<<1152, 256, 0, stream>>>(
        xT, Wp1, out1, 128, 0, bn1_g, bn1_b, bn1_m, bn1_v, nullptr);
    // q (qscale folded in weights)
    gemm_mfma<false,false,false><<<1152, 256, 0, stream>>>(
        out1, Wq, qbuf, 128, 0, nullptr,nullptr,nullptr,nullptr,nullptr);
    // k, v
    gemm_mfma<false,false,false><<<1152, 256, 0, stream>>>(
        out1, Wk, kv, 256, 0, nullptr,nullptr,nullptr,nullptr,nullptr);
    gemm_mfma<false,false,false><<<1152, 256, 0, stream>>>(
        out1, Wv, kv, 256, 128, nullptr,nullptr,nullptr,nullptr,nullptr);

    attn_kernel<<<4608, 512, 0, stream>>>(qbuf, (const u16*)kv, rel_h, rel_w, attnout);

    // out projection + bias + ReLU
    gemm_mfma<false,true,true><<<1152, 256, 0, stream>>>(
        attnout, Wo, out2, 128, 0, nullptr,nullptr,nullptr,nullptr, to_ob);

    // conv3 (3x3 convT) + BN3 + residual + ReLU -> NCHW f32 d_out
    conv3_mfma<<<1152, 256, 0, stream>>>(out2, W3p, x, (float*)d_out,
                                         bn3_g, bn3_b, bn3_m, bn3_v);
}

// Round 6
// 269.729 us; speedup vs baseline: 14.6126x; 1.6598x over previous
//
#include <hip/hip_runtime.h>
#include <hip/hip_bf16.h>

using bf16 = __hip_bfloat16;
typedef unsigned short u16;
typedef unsigned int   u32;
typedef __attribute__((ext_vector_type(8))) short short8;   // 8 bf16 = 4 VGPRs (MFMA A/B frag)
typedef __attribute__((ext_vector_type(4))) float f32x4;    // MFMA C/D frag

#define B_N 2
#define CCH 128
#define HH 192
#define WW 192
#define HWS (HH*WW)          // 36864
#define NPIX (B_N*HWS)       // 73728
#define NBLKS 576            // 24*24 halo blocks per batch
#define EPSV 1e-5f
#define LDW 136              // LDS row stride (u16) for MFMA tiles: 272B, 16B-aligned

__device__ __forceinline__ float b2f(bf16 v){ return __bfloat162float(v); }
__device__ __forceinline__ bf16  f2b(float v){ return __float2bfloat16(v); }
__device__ __forceinline__ float lo16(u32 u){ union{u32 i; float f;} x; x.i = u << 16;        return x.f; }
__device__ __forceinline__ float hi16(u32 u){ union{u32 i; float f;} x; x.i = u & 0xffff0000u; return x.f; }
__device__ __forceinline__ u32 pck(float a, float b){
    bf16 x = f2b(a), y = f2b(b);
    return (u32)*(u16*)&x | ((u32)*(u16*)&y << 16);
}

// ---------------------------------------------------------------------------
// x NCHW f32 -> xT [P][128] bf16
// ---------------------------------------------------------------------------
__global__ __launch_bounds__(256) void transpose_in(const float* __restrict__ x,
                                                    bf16* __restrict__ xT)
{
    __shared__ float tile[128][17];
    const int t   = threadIdx.x;
    const int hw0 = blockIdx.x * 16;
    const int n   = hw0 / HWS;
    const int hwl = hw0 - n*HWS;
    const int px = t & 15, cb = t >> 4;
    #pragma unroll
    for (int r = 0; r < 8; ++r){
        int ci = r*16 + cb;
        tile[ci][px] = x[(size_t)(n*CCH + ci)*HWS + hwl + px];
    }
    __syncthreads();
    const int pix = t >> 4, cig = t & 15;
    uint4 pk;
    pk.x = pck(tile[cig*8+0][pix], tile[cig*8+1][pix]);
    pk.y = pck(tile[cig*8+2][pix], tile[cig*8+3][pix]);
    pk.z = pck(tile[cig*8+4][pix], tile[cig*8+5][pix]);
    pk.w = pck(tile[cig*8+6][pix], tile[cig*8+7][pix]);
    *(uint4*)&xT[(size_t)(hw0 + pix)*CCH + cig*8] = pk;
}

// ---------------------------------------------------------------------------
// Weight prep -> bf16 blob, all [co][ci]:
// [0,16K) W1 | [16K,32K) Wq*qscale | [32K,48K) Wk | [48K,64K) Wv | [64K,80K) Wo
// [80K,224K) W3 [tap][co][ci]
// ---------------------------------------------------------------------------
__global__ __launch_bounds__(256) void prep_w(
    const float* __restrict__ w1, const float* __restrict__ to_q,
    const float* __restrict__ to_kv, const float* __restrict__ to_ow,
    const float* __restrict__ w3, bf16* __restrict__ wb)
{
    int i = blockIdx.x*256 + threadIdx.x;      // < 229376
    float v;
    if (i < 16384){       int co=(i>>7)&127, ci=i&127;      v = w1[ci*128+co]; }
    else if (i < 32768){  int r=i-16384; int co=r>>7, ci=r&127; v = to_q[ci*128+co]*0.17677669529663687f; }
    else if (i < 49152){  int r=i-32768; int co=r>>7, ci=r&127; v = to_kv[ci*256+co]; }
    else if (i < 65536){  int r=i-49152; int co=r>>7, ci=r&127; v = to_kv[ci*256+128+co]; }
    else if (i < 81920){  int r=i-65536; int co=r>>7, ci=r&127; v = to_ow[ci*128+co]; }
    else { int r=i-81920; int tap=r>>14, co=(r>>7)&127, ci=r&127; int a=tap/3, b=tap-a*3;
           v = w3[((size_t)(ci*128+co)*3+a)*3+b]; }
    wb[i] = f2b(v);
}

// ---------------------------------------------------------------------------
// MFMA channel GEMM (verified r5): out[pix][choff+co] = op(sum_ci in[pix][ci]*W[co][ci])
// ---------------------------------------------------------------------------
template<bool DO_BN, bool DO_BIAS, bool DO_RELU>
__global__ __launch_bounds__(256) void gemm_mfma(
    const bf16* __restrict__ inp, const bf16* __restrict__ Wp,
    bf16* __restrict__ outp, int cstride, int choff,
    const float* __restrict__ bn_g, const float* __restrict__ bn_b,
    const float* __restrict__ bn_m, const float* __restrict__ bn_v,
    const float* __restrict__ bias)
{
    __shared__ u16 sW[128*LDW];
    __shared__ u16 sX[64*LDW];
    const int tid  = threadIdx.x;
    const int pix0 = blockIdx.x * 64;
    const int lane = tid & 63;
    const int ln = lane & 15, g = lane >> 4;
    const int cow = (tid >> 6) * 32;

    #pragma unroll
    for (int r = 0; r < 8; ++r){
        int e = tid + r*256; int row = e>>4, grp = e&15;
        *(uint4*)&sW[row*LDW + grp*8] = *(const uint4*)&Wp[row*128 + grp*8];
    }
    #pragma unroll
    for (int r = 0; r < 4; ++r){
        int e = tid + r*256; int row = e>>4, grp = e&15;
        *(uint4*)&sX[row*LDW + grp*8] = *(const uint4*)&inp[(size_t)(pix0+row)*CCH + grp*8];
    }
    __syncthreads();

    f32x4 acc[4][2];
    #pragma unroll
    for (int mi=0;mi<4;mi++)
        #pragma unroll
        for (int ni=0;ni<2;ni++) acc[mi][ni] = (f32x4){0.f,0.f,0.f,0.f};

    #pragma unroll
    for (int kk = 0; kk < 4; ++kk){
        short8 fa[4], fb[2];
        #pragma unroll
        for (int mi=0;mi<4;mi++)
            fa[mi] = *(const short8*)&sX[(mi*16+ln)*LDW + kk*32 + g*8];
        #pragma unroll
        for (int ni=0;ni<2;ni++)
            fb[ni] = *(const short8*)&sW[(cow+ni*16+ln)*LDW + kk*32 + g*8];
        #pragma unroll
        for (int mi=0;mi<4;mi++)
            #pragma unroll
            for (int ni=0;ni<2;ni++)
                acc[mi][ni] = __builtin_amdgcn_mfma_f32_16x16x32_bf16(fa[mi], fb[ni], acc[mi][ni], 0, 0, 0);
    }

    float sc[2], bb[2];
    #pragma unroll
    for (int ni=0;ni<2;ni++){
        int co = cow + ni*16 + ln;
        sc[ni] = 1.f; bb[ni] = 0.f;
        if (DO_BN){ float sg = bn_g[co]*rsqrtf(bn_v[co]+EPSV); sc[ni]=sg; bb[ni]=bn_b[co]-bn_m[co]*sg; }
        if (DO_BIAS) bb[ni] += bias[co];
    }
    #pragma unroll
    for (int mi=0;mi<4;mi++)
        #pragma unroll
        for (int ni=0;ni<2;ni++)
            #pragma unroll
            for (int j=0;j<4;j++){
                int pix = pix0 + mi*16 + g*4 + j;
                int co  = cow + ni*16 + ln;
                float v = acc[mi][ni][j]*sc[ni] + bb[ni];
                if (DO_RELU) v = fmaxf(v, 0.f);
                outp[(size_t)pix*cstride + choff + co] = f2b(v);
            }
}

// ---------------------------------------------------------------------------
// conv3 transposed (pad=1) via 9-tap MFMA + BN3 + residual + ReLU (verified r5)
// ---------------------------------------------------------------------------
__global__ __launch_bounds__(256) void conv3_mfma(
    const bf16* __restrict__ inp, const bf16* __restrict__ W3p,
    const float* __restrict__ xin, float* __restrict__ outp,
    const float* __restrict__ g3, const float* __restrict__ b3,
    const float* __restrict__ m3, const float* __restrict__ v3)
{
    __shared__ u16 sW[128*LDW];
    __shared__ u16 sX[64*LDW];
    const int tid = threadIdx.x;
    const int P0  = blockIdx.x * 64;
    const int n   = P0 / HWS;
    const int hwb = P0 - n*HWS;
    const int h = hwb / WW, wb = hwb - h*WW;
    const int lane = tid & 63, ln = lane & 15, g = lane >> 4;
    const int cow = (tid >> 6) * 32;

    f32x4 acc[2][4];
    #pragma unroll
    for (int mi=0;mi<2;mi++)
        #pragma unroll
        for (int ni=0;ni<4;ni++) acc[mi][ni] = (f32x4){0.f,0.f,0.f,0.f};

    for (int tap = 0; tap < 9; ++tap){
        const int a = tap/3, b = tap - a*3;
        const int hs = h + 1 - a;
        if (hs < 0 || hs >= HH) continue;
        const int ws0 = wb + 1 - b;
        __syncthreads();
        #pragma unroll
        for (int r = 0; r < 8; ++r){
            int e = tid + r*256; int row = e>>4, grp = e&15;
            *(uint4*)&sW[row*LDW + grp*8] = *(const uint4*)&W3p[tap*16384 + row*128 + grp*8];
        }
        #pragma unroll
        for (int r = 0; r < 4; ++r){
            int e = tid + r*256; int row = e>>4, grp = e&15;
            int wsrc = ws0 + row;
            uint4 val = {0u,0u,0u,0u};
            if (wsrc >= 0 && wsrc < WW)
                val = *(const uint4*)&inp[(size_t)(n*HWS + hs*WW + wsrc)*CCH + grp*8];
            *(uint4*)&sX[row*LDW + grp*8] = val;
        }
        __syncthreads();
        #pragma unroll
        for (int kk = 0; kk < 4; ++kk){
            short8 fa[2], fb[4];
            #pragma unroll
            for (int mi=0;mi<2;mi++)
                fa[mi] = *(const short8*)&sW[(cow+mi*16+ln)*LDW + kk*32 + g*8];
            #pragma unroll
            for (int ni=0;ni<4;ni++)
                fb[ni] = *(const short8*)&sX[(ni*16+ln)*LDW + kk*32 + g*8];
            #pragma unroll
            for (int mi=0;mi<2;mi++)
                #pragma unroll
                for (int ni=0;ni<4;ni++)
                    acc[mi][ni] = __builtin_amdgcn_mfma_f32_16x16x32_bf16(fa[mi], fb[ni], acc[mi][ni], 0, 0, 0);
        }
    }

    #pragma unroll
    for (int mi=0;mi<2;mi++)
        #pragma unroll
        for (int j=0;j<4;j++){
            int co = cow + mi*16 + g*4 + j;
            float sg = g3[co]*rsqrtf(v3[co]+EPSV);
            float bc = b3[co] - m3[co]*sg;
            #pragma unroll
            for (int ni=0;ni<4;ni++){
                int pixl = hwb + ni*16 + ln;
                size_t idx = (size_t)(n*CCH + co)*HWS + pixl;
                float v = acc[mi][ni][j]*sg + bc + xin[idx];
                outp[idx] = fmaxf(v, 0.f);
            }
        }
}

// ---------------------------------------------------------------------------
// MFMA halo attention. One block per (batch, 8x8 block, head), 512 thr = 8 waves.
// QK^T: wave w owns j-slice [w*32, w*32+32): 4 m-tiles x 2 n-tiles, K=32 (8 MFMAs).
// Softmax: bias+mask on regs; row reduce = shfl_xor over ln + cross-wave LDS.
// P~ (unnorm, <=1) -> bf16 LDS [64][264]; PV: wave w = (mt=w>>1, nt=w&1), K=256
// (8 MFMAs) over sP x sVT; epilogue scales by 1/rowsum. No min-blocks (r2 lesson).
// ---------------------------------------------------------------------------
__global__ __launch_bounds__(512) void attn_kernel(
    const bf16* __restrict__ Qb, const u16* __restrict__ KVb,
    const float* __restrict__ relh, const float* __restrict__ relw,
    bf16* __restrict__ outp)
{
    // LDS (61440 B):
    //  [0,5120)      sQb  [64][40] u16    (dead after QK^T)
    //  [5120,25600)  sK   [256][40] u16   (dead after QK^T)
    //  [25600,29568) sRHT [32][31] f32    (dead after table build)
    //  [29568,33536) sRWT [32][31] f32    (dead after table build)
    //  [0,33792)     sP   [64][264] u16   OVERLAY of the above
    //  [33792,50688) sVT  [32][264] u16
    //  [50688,54784) tRH  [64][16] f32
    //  [54784,58880) tRW  [64][16] f32
    //  [58880,60928) wred [8][64] f32
    //  [60928,61184) gmax [64] f32
    //  [61184,61440) gsinv[64] f32
    __shared__ __align__(16) char smem[61440];
    u16*   sQb  = (u16*)  (smem + 0);
    u16*   sK   = (u16*)  (smem + 5120);
    float* sRHT = (float*)(smem + 25600);
    float* sRWT = (float*)(smem + 29568);
    u16*   sP   = (u16*)  (smem + 0);
    u16*   sVT  = (u16*)  (smem + 33792);
    float* tRH  = (float*)(smem + 50688);
    float* tRW  = (float*)(smem + 54784);
    float* wred = (float*)(smem + 58880);
    float* gmax = (float*)(smem + 60928);
    float* gsin = (float*)(smem + 61184);

    const int tid  = threadIdx.x;
    const int bid  = blockIdx.x;
    const int head = bid & 3;
    const int t    = bid >> 2;
    const int n    = t / NBLKS;
    const int blk  = t - n*NBLKS;
    const int bi = blk / 24, bj = blk - bi*24;
    const int row0 = bi*8 - 4, col0 = bj*8 - 4;
    const int ch0 = head*32;
    const int wv = tid >> 6, lane = tid & 63, ln = lane & 15, g = lane >> 4;

    // ---- stage rel tables (f32), Q (bf16 rows), K (rows), V^T ----
    for (int e = tid; e < 992; e += 512){
        int r = e >> 5, d = e & 31;
        sRHT[d*31 + r] = relh[e];
        sRWT[d*31 + r] = relw[e];
    }
    {   // Q: 64 q x 32 d = 2048 u16 -> one uint2 per thread
        int qq = tid >> 3, db = tid & 7;
        size_t P = (size_t)n*HWS + (bi*8 + (qq>>3))*WW + bj*8 + (qq&7);
        *(uint2*)&sQb[qq*40 + db*4] = *(const uint2*)&Qb[P*CCH + ch0 + db*4];
    }
    #pragma unroll
    for (int r = 0; r < 4; ++r){   // K,V: 256 wp x 8 dblk
        int e = tid + r*512;
        int wp = e >> 3, db = e & 7;
        int rr = row0 + (wp>>4), cc2 = col0 + (wp&15);
        uint2 kv2 = {0u,0u}, vv2 = {0u,0u};
        if (rr>=0 && rr<HH && cc2>=0 && cc2<WW){
            size_t P = (size_t)n*HWS + rr*WW + cc2;
            kv2 = *(const uint2*)&KVb[P*256 + ch0 + db*4];
            vv2 = *(const uint2*)&KVb[P*256 + 128 + ch0 + db*4];
        }
        *(uint2*)&sK[wp*40 + db*4] = kv2;
        sVT[(db*4+0)*264 + wp] = (u16)(vv2.x & 0xffff);
        sVT[(db*4+1)*264 + wp] = (u16)(vv2.x >> 16);
        sVT[(db*4+2)*264 + wp] = (u16)(vv2.y & 0xffff);
        sVT[(db*4+3)*264 + wp] = (u16)(vv2.y >> 16);
    }
    __syncthreads();

    // ---- rel-logit tables: 2048 dots of 32 (bf16 Q x f32 rel) ----
    #pragma unroll
    for (int tt = 0; tt < 4; ++tt){
        int id  = tid + tt*512;
        int tb  = id >> 10;
        int rem = id & 1023;
        int qq  = rem >> 4, ww = rem & 15;
        int bq  = tb ? (qq & 7) : (qq >> 3);
        int r   = 15 + ww - bq;
        const u32* qrow = (const u32*)&sQb[qq*40];
        float acc = 0.f;
        if (tb == 0){
            #pragma unroll
            for (int c = 0; c < 16; ++c){
                u32 u = qrow[c];
                acc += lo16(u)*sRHT[(2*c)*31 + r] + hi16(u)*sRHT[(2*c+1)*31 + r];
            }
            tRH[qq*16 + ww] = acc;
        } else {
            #pragma unroll
            for (int c = 0; c < 16; ++c){
                u32 u = qrow[c];
                acc += lo16(u)*sRWT[(2*c)*31 + r] + hi16(u)*sRWT[(2*c+1)*31 + r];
            }
            tRW[qq*16 + ww] = acc;
        }
    }
    __syncthreads();

    // ---- QK^T MFMA: wave wv -> j in [wv*32, wv*32+32) ----
    f32x4 accs[4][2];
    {
        short8 fa[4], fb[2];
        #pragma unroll
        for (int mt=0;mt<4;mt++)
            fa[mt] = *(const short8*)&sQb[(mt*16+ln)*40 + g*8];
        #pragma unroll
        for (int nt=0;nt<2;nt++)
            fb[nt] = *(const short8*)&sK[(wv*32+nt*16+ln)*40 + g*8];
        #pragma unroll
        for (int mt=0;mt<4;mt++)
            #pragma unroll
            for (int nt=0;nt<2;nt++)
                accs[mt][nt] = __builtin_amdgcn_mfma_f32_16x16x32_bf16(
                    fa[mt], fb[nt], (f32x4){0.f,0.f,0.f,0.f}, 0, 0, 0);
    }

    // ---- bias + mask (regs) ----
    #pragma unroll
    for (int nt=0;nt<2;nt++){
        int j  = wv*32 + nt*16 + ln;
        int iw = j >> 4, jw = j & 15;
        int rr = row0 + iw, cc2 = col0 + jw;
        bool ok = (rr>=0 && rr<HH && cc2>=0 && cc2<WW);
        #pragma unroll
        for (int mt=0;mt<4;mt++)
            #pragma unroll
            for (int r=0;r<4;r++){
                int q = mt*16 + g*4 + r;
                float s = accs[mt][nt][r];
                accs[mt][nt][r] = ok ? (s + tRH[q*16+iw] + tRW[q*16+jw]) : -3.0e38f;
            }
    }

    // ---- wave row-max (over ln) -> wred ----
    float rmax[4][4];
    #pragma unroll
    for (int mt=0;mt<4;mt++)
        #pragma unroll
        for (int r=0;r<4;r++){
            float m = fmaxf(accs[mt][0][r], accs[mt][1][r]);
            m = fmaxf(m, __shfl_xor(m, 1));
            m = fmaxf(m, __shfl_xor(m, 2));
            m = fmaxf(m, __shfl_xor(m, 4));
            m = fmaxf(m, __shfl_xor(m, 8));
            rmax[mt][r] = m;
        }
    if (ln == 0){
        #pragma unroll
        for (int mt=0;mt<4;mt++)
            #pragma unroll
            for (int r=0;r<4;r++)
                wred[wv*64 + mt*16 + g*4 + r] = rmax[mt][r];
    }
    __syncthreads();
    if (tid < 64){
        float m = wred[tid];
        #pragma unroll
        for (int w=1;w<8;w++) m = fmaxf(m, wred[w*64+tid]);
        gmax[tid] = m;
    }
    __syncthreads();

    // ---- exp + row-sum + write P~ (bf16) into sP overlay ----
    float rsum[4][4];
    #pragma unroll
    for (int mt=0;mt<4;mt++)
        #pragma unroll
        for (int r=0;r<4;r++){
            int q = mt*16 + g*4 + r;
            float qm = gmax[q];
            float p0 = __expf(accs[mt][0][r] - qm);
            float p1 = __expf(accs[mt][1][r] - qm);
            sP[q*264 + wv*32 +      ln] = *(u16*)&(*(bf16*)&(p0)); // placeholder, replaced below
            rsum[mt][r] = p0 + p1;
            accs[mt][0][r] = p0;
            accs[mt][1][r] = p1;
        }
    // proper bf16 stores (two per (mt,r))
    #pragma unroll
    for (int mt=0;mt<4;mt++)
        #pragma unroll
        for (int r=0;r<4;r++){
            int q = mt*16 + g*4 + r;
            bf16 b0 = f2b(accs[mt][0][r]);
            bf16 b1 = f2b(accs[mt][1][r]);
            sP[q*264 + wv*32 +      ln] = *(u16*)&b0;
            sP[q*264 + wv*32 + 16 + ln] = *(u16*)&b1;
        }
    #pragma unroll
    for (int mt=0;mt<4;mt++)
        #pragma unroll
        for (int r=0;r<4;r++){
            float s = rsum[mt][r];
            s += __shfl_xor(s, 1);
            s += __shfl_xor(s, 2);
            s += __shfl_xor(s, 4);
            s += __shfl_xor(s, 8);
            rsum[mt][r] = s;
        }
    if (ln == 0){
        #pragma unroll
        for (int mt=0;mt<4;mt++)
            #pragma unroll
            for (int r=0;r<4;r++)
                wred[wv*64 + mt*16 + g*4 + r] = rsum[mt][r];
    }
    __syncthreads();
    if (tid < 64){
        float s = wred[tid];
        #pragma unroll
        for (int w=1;w<8;w++) s += wred[w*64+tid];
        gsin[tid] = 1.f / s;
    }
    __syncthreads();

    // ---- PV MFMA: wave wv -> (mt = wv>>1, nt = wv&1), K=256 ----
    {
        const int mt = wv >> 1, nt = wv & 1;
        f32x4 acco = (f32x4){0.f,0.f,0.f,0.f};
        #pragma unroll
        for (int ks=0;ks<8;ks++){
            short8 fa = *(const short8*)&sP [(mt*16+ln)*264 + ks*32 + g*8];
            short8 fb = *(const short8*)&sVT[(nt*16+ln)*264 + ks*32 + g*8];
            acco = __builtin_amdgcn_mfma_f32_16x16x32_bf16(fa, fb, acco, 0, 0, 0);
        }
        const int d = nt*16 + ln;
        #pragma unroll
        for (int r=0;r<4;r++){
            int q = mt*16 + g*4 + r;
            size_t P = (size_t)n*HWS + (bi*8 + (q>>3))*WW + bj*8 + (q&7);
            outp[P*CCH + ch0 + d] = f2b(acco[r] * gsin[q]);
        }
    }
}

// ---------------------------------------------------------------------------
extern "C" void kernel_launch(void* const* d_in, const int* in_sizes, int n_in,
                              void* d_out, int out_size, void* d_ws, size_t ws_size,
                              hipStream_t stream)
{
    (void)in_sizes; (void)n_in; (void)out_size; (void)ws_size;
    const float* x      = (const float*)d_in[0];
    const float* w1     = (const float*)d_in[1];
    const float* bn1_g  = (const float*)d_in[2];
    const float* bn1_b  = (const float*)d_in[3];
    const float* bn1_m  = (const float*)d_in[4];
    const float* bn1_v  = (const float*)d_in[5];
    const float* to_q   = (const float*)d_in[6];
    const float* to_kv  = (const float*)d_in[7];
    const float* to_ow  = (const float*)d_in[8];
    const float* to_ob  = (const float*)d_in[9];
    const float* rel_h  = (const float*)d_in[10];
    const float* rel_w  = (const float*)d_in[11];
    const float* w3     = (const float*)d_in[12];
    const float* bn3_g  = (const float*)d_in[13];
    const float* bn3_b  = (const float*)d_in[14];
    const float* bn3_m  = (const float*)d_in[15];
    const float* bn3_v  = (const float*)d_in[16];

    char* ws   = (char*)d_ws;
    bf16* out1 = (bf16*)(ws + 0);              // [P][128]; later reused as out2
    bf16* kv   = (bf16*)(ws + 18874368);       // [P][256]
    bf16* xT   = (bf16*)(ws + 56623104);       // [P][128]
    bf16* wb   = (bf16*)(ws + 75497472);       // weights (458752 B)
    bf16* Wp1 = wb;            bf16* Wq = wb + 16384;  bf16* Wk = wb + 32768;
    bf16* Wv  = wb + 49152;    bf16* Wo = wb + 65536;  bf16* W3p = wb + 81920;
    bf16* qbuf    = (bf16*)d_out;              // d_out as scratch until conv3
    bf16* attnout = (bf16*)d_out + 9437184;
    bf16* out2    = out1;

    transpose_in<<<4608, 256, 0, stream>>>(x, xT);
    prep_w<<<896, 256, 0, stream>>>(w1, to_q, to_kv, to_ow, w3, wb);

    gemm_mfma<true,false,true><<<1152, 256, 0, stream>>>(
        xT, Wp1, out1, 128, 0, bn1_g, bn1_b, bn1_m, bn1_v, nullptr);
    gemm_mfma<false,false,false><<<1152, 256, 0, stream>>>(
        out1, Wq, qbuf, 128, 0, nullptr,nullptr,nullptr,nullptr,nullptr);
    gemm_mfma<false,false,false><<<1152, 256, 0, stream>>>(
        out1, Wk, kv, 256, 0, nullptr,nullptr,nullptr,nullptr,nullptr);
    gemm_mfma<false,false,false><<<1152, 256, 0, stream>>>(
        out1, Wv, kv, 256, 128, nullptr,nullptr,nullptr,nullptr,nullptr);

    attn_kernel<<<4608, 512, 0, stream>>>(qbuf, (const u16*)kv, rel_h, rel_w, attnout);

    gemm_mfma<false,true,true><<<1152, 256, 0, stream>>>(
        attnout, Wo, out2, 128, 0, nullptr,nullptr,nullptr,nullptr, to_ob);

    conv3_mfma<<<1152, 256, 0, stream>>>(out2, W3p, x, (float*)d_out,
                                         bn3_g, bn3_b, bn3_m, bn3_v);
}

// Round 7
// 177.601 us; speedup vs baseline: 22.1926x; 1.5187x over previous
//
#include <hip/hip_runtime.h>
#include <hip/hip_bf16.h>

using bf16 = __hip_bfloat16;
typedef unsigned short u16;
typedef unsigned int   u32;
typedef __attribute__((ext_vector_type(8))) short short8;   // 8 bf16 = 4 VGPRs (MFMA A/B frag)
typedef __attribute__((ext_vector_type(4))) float f32x4;    // MFMA C/D frag

#define B_N 2
#define CCH 128
#define HH 192
#define WW 192
#define HWS (HH*WW)          // 36864
#define NPIX (B_N*HWS)       // 73728
#define NBLKS 576            // 24*24 halo blocks per batch
#define EPSV 1e-5f
#define LDW 136              // LDS row stride (u16) for MFMA tiles

__device__ __forceinline__ float b2f(bf16 v){ return __bfloat162float(v); }
__device__ __forceinline__ bf16  f2b(float v){ return __float2bfloat16(v); }
__device__ __forceinline__ u16  bits(bf16 v){ return *(u16*)&v; }
__device__ __forceinline__ float lo16(u32 u){ union{u32 i; float f;} x; x.i = u << 16;        return x.f; }
__device__ __forceinline__ float hi16(u32 u){ union{u32 i; float f;} x; x.i = u & 0xffff0000u; return x.f; }
__device__ __forceinline__ u32 pck(float a, float b){
    bf16 x = f2b(a), y = f2b(b);
    return (u32)*(u16*)&x | ((u32)*(u16*)&y << 16);
}

// ---------------------------------------------------------------------------
// x NCHW f32 -> xT [P][128] bf16
// ---------------------------------------------------------------------------
__global__ __launch_bounds__(256) void transpose_in(const float* __restrict__ x,
                                                    bf16* __restrict__ xT)
{
    __shared__ float tile[128][17];
    const int t   = threadIdx.x;
    const int hw0 = blockIdx.x * 16;
    const int n   = hw0 / HWS;
    const int hwl = hw0 - n*HWS;
    const int px = t & 15, cb = t >> 4;
    #pragma unroll
    for (int r = 0; r < 8; ++r){
        int ci = r*16 + cb;
        tile[ci][px] = x[(size_t)(n*CCH + ci)*HWS + hwl + px];
    }
    __syncthreads();
    const int pix = t >> 4, cig = t & 15;
    uint4 pk;
    pk.x = pck(tile[cig*8+0][pix], tile[cig*8+1][pix]);
    pk.y = pck(tile[cig*8+2][pix], tile[cig*8+3][pix]);
    pk.z = pck(tile[cig*8+4][pix], tile[cig*8+5][pix]);
    pk.w = pck(tile[cig*8+6][pix], tile[cig*8+7][pix]);
    *(uint4*)&xT[(size_t)(hw0 + pix)*CCH + cig*8] = pk;
}

// ---------------------------------------------------------------------------
// Weight prep -> bf16 blob, all [co][ci]:
// [0,16K) W1 | [16K,32K) Wq*qscale | [32K,48K) Wk | [48K,64K) Wv | [64K,80K) Wo
// [80K,224K) W3 [tap][co][ci]
// ---------------------------------------------------------------------------
__global__ __launch_bounds__(256) void prep_w(
    const float* __restrict__ w1, const float* __restrict__ to_q,
    const float* __restrict__ to_kv, const float* __restrict__ to_ow,
    const float* __restrict__ w3, bf16* __restrict__ wb)
{
    int i = blockIdx.x*256 + threadIdx.x;      // < 229376
    float v;
    if (i < 16384){       int co=(i>>7)&127, ci=i&127;      v = w1[ci*128+co]; }
    else if (i < 32768){  int r=i-16384; int co=r>>7, ci=r&127; v = to_q[ci*128+co]*0.17677669529663687f; }
    else if (i < 49152){  int r=i-32768; int co=r>>7, ci=r&127; v = to_kv[ci*256+co]; }
    else if (i < 65536){  int r=i-49152; int co=r>>7, ci=r&127; v = to_kv[ci*256+128+co]; }
    else if (i < 81920){  int r=i-65536; int co=r>>7, ci=r&127; v = to_ow[ci*128+co]; }
    else { int r=i-81920; int tap=r>>14, co=(r>>7)&127, ci=r&127; int a=tap/3, b=tap-a*3;
           v = w3[((size_t)(ci*128+co)*3+a)*3+b]; }
    wb[i] = f2b(v);
}

// ---------------------------------------------------------------------------
// MFMA channel GEMM (verified r5/r6). blockIdx.y selects a 128-co weight slab
// (Wp + y*16384, choff + y*128) -> fused q|k|v in one launch with grid.y=3.
// ---------------------------------------------------------------------------
template<bool DO_BN, bool DO_BIAS, bool DO_RELU>
__global__ __launch_bounds__(256) void gemm_mfma(
    const bf16* __restrict__ inp, const bf16* __restrict__ Wp,
    bf16* __restrict__ outp, int cstride, int choff,
    const float* __restrict__ bn_g, const float* __restrict__ bn_b,
    const float* __restrict__ bn_m, const float* __restrict__ bn_v,
    const float* __restrict__ bias)
{
    Wp    += (size_t)blockIdx.y * 16384;
    choff += blockIdx.y * 128;
    __shared__ u16 sW[128*LDW];
    __shared__ u16 sX[64*LDW];
    const int tid  = threadIdx.x;
    const int pix0 = blockIdx.x * 64;
    const int lane = tid & 63;
    const int ln = lane & 15, g = lane >> 4;
    const int cow = (tid >> 6) * 32;

    #pragma unroll
    for (int r = 0; r < 8; ++r){
        int e = tid + r*256; int row = e>>4, grp = e&15;
        *(uint4*)&sW[row*LDW + grp*8] = *(const uint4*)&Wp[row*128 + grp*8];
    }
    #pragma unroll
    for (int r = 0; r < 4; ++r){
        int e = tid + r*256; int row = e>>4, grp = e&15;
        *(uint4*)&sX[row*LDW + grp*8] = *(const uint4*)&inp[(size_t)(pix0+row)*CCH + grp*8];
    }
    __syncthreads();

    f32x4 acc[4][2];
    #pragma unroll
    for (int mi=0;mi<4;mi++)
        #pragma unroll
        for (int ni=0;ni<2;ni++) acc[mi][ni] = (f32x4){0.f,0.f,0.f,0.f};

    #pragma unroll
    for (int kk = 0; kk < 4; ++kk){
        short8 fa[4], fb[2];
        #pragma unroll
        for (int mi=0;mi<4;mi++)
            fa[mi] = *(const short8*)&sX[(mi*16+ln)*LDW + kk*32 + g*8];
        #pragma unroll
        for (int ni=0;ni<2;ni++)
            fb[ni] = *(const short8*)&sW[(cow+ni*16+ln)*LDW + kk*32 + g*8];
        #pragma unroll
        for (int mi=0;mi<4;mi++)
            #pragma unroll
            for (int ni=0;ni<2;ni++)
                acc[mi][ni] = __builtin_amdgcn_mfma_f32_16x16x32_bf16(fa[mi], fb[ni], acc[mi][ni], 0, 0, 0);
    }

    float sc[2], bb[2];
    #pragma unroll
    for (int ni=0;ni<2;ni++){
        int co = cow + ni*16 + ln;
        sc[ni] = 1.f; bb[ni] = 0.f;
        if (DO_BN){ float sg = bn_g[co]*rsqrtf(bn_v[co]+EPSV); sc[ni]=sg; bb[ni]=bn_b[co]-bn_m[co]*sg; }
        if (DO_BIAS) bb[ni] += bias[co];
    }
    #pragma unroll
    for (int mi=0;mi<4;mi++)
        #pragma unroll
        for (int ni=0;ni<2;ni++)
            #pragma unroll
            for (int j=0;j<4;j++){
                int pix = pix0 + mi*16 + g*4 + j;
                int co  = cow + ni*16 + ln;
                float v = acc[mi][ni][j]*sc[ni] + bb[ni];
                if (DO_RELU) v = fmaxf(v, 0.f);
                outp[(size_t)pix*cstride + choff + co] = f2b(v);
            }
}

// ---------------------------------------------------------------------------
// conv3 transposed (pad=1) via 9-tap MFMA + BN3 + residual + ReLU (verified r5)
// ---------------------------------------------------------------------------
__global__ __launch_bounds__(256) void conv3_mfma(
    const bf16* __restrict__ inp, const bf16* __restrict__ W3p,
    const float* __restrict__ xin, float* __restrict__ outp,
    const float* __restrict__ g3, const float* __restrict__ b3,
    const float* __restrict__ m3, const float* __restrict__ v3)
{
    __shared__ u16 sW[128*LDW];
    __shared__ u16 sX[64*LDW];
    const int tid = threadIdx.x;
    const int P0  = blockIdx.x * 64;
    const int n   = P0 / HWS;
    const int hwb = P0 - n*HWS;
    const int h = hwb / WW, wb = hwb - h*WW;
    const int lane = tid & 63, ln = lane & 15, g = lane >> 4;
    const int cow = (tid >> 6) * 32;

    f32x4 acc[2][4];
    #pragma unroll
    for (int mi=0;mi<2;mi++)
        #pragma unroll
        for (int ni=0;ni<4;ni++) acc[mi][ni] = (f32x4){0.f,0.f,0.f,0.f};

    for (int tap = 0; tap < 9; ++tap){
        const int a = tap/3, b = tap - a*3;
        const int hs = h + 1 - a;
        if (hs < 0 || hs >= HH) continue;
        const int ws0 = wb + 1 - b;
        __syncthreads();
        #pragma unroll
        for (int r = 0; r < 8; ++r){
            int e = tid + r*256; int row = e>>4, grp = e&15;
            *(uint4*)&sW[row*LDW + grp*8] = *(const uint4*)&W3p[tap*16384 + row*128 + grp*8];
        }
        #pragma unroll
        for (int r = 0; r < 4; ++r){
            int e = tid + r*256; int row = e>>4, grp = e&15;
            int wsrc = ws0 + row;
            uint4 val = {0u,0u,0u,0u};
            if (wsrc >= 0 && wsrc < WW)
                val = *(const uint4*)&inp[(size_t)(n*HWS + hs*WW + wsrc)*CCH + grp*8];
            *(uint4*)&sX[row*LDW + grp*8] = val;
        }
        __syncthreads();
        #pragma unroll
        for (int kk = 0; kk < 4; ++kk){
            short8 fa[2], fb[4];
            #pragma unroll
            for (int mi=0;mi<2;mi++)
                fa[mi] = *(const short8*)&sW[(cow+mi*16+ln)*LDW + kk*32 + g*8];
            #pragma unroll
            for (int ni=0;ni<4;ni++)
                fb[ni] = *(const short8*)&sX[(ni*16+ln)*LDW + kk*32 + g*8];
            #pragma unroll
            for (int mi=0;mi<2;mi++)
                #pragma unroll
                for (int ni=0;ni<4;ni++)
                    acc[mi][ni] = __builtin_amdgcn_mfma_f32_16x16x32_bf16(fa[mi], fb[ni], acc[mi][ni], 0, 0, 0);
        }
    }

    #pragma unroll
    for (int mi=0;mi<2;mi++)
        #pragma unroll
        for (int j=0;j<4;j++){
            int co = cow + mi*16 + g*4 + j;
            float sg = g3[co]*rsqrtf(v3[co]+EPSV);
            float bc = b3[co] - m3[co]*sg;
            #pragma unroll
            for (int ni=0;ni<4;ni++){
                int pixl = hwb + ni*16 + ln;
                size_t idx = (size_t)(n*CCH + co)*HWS + pixl;
                float v = acc[mi][ni][j]*sg + bc + xin[idx];
                outp[idx] = fmaxf(v, 0.f);
            }
        }
}

// ---------------------------------------------------------------------------
// MFMA halo attention v2. One block per (batch, block, head), 512 thr = 8 waves.
// SWAPPED QK^T: C[j][q] = mfma(K, Q) -> lane owns one q-column, 32 j's ->
// softmax stats are in-thread + 2 shfl + 2-entry LDS combine.
// Rel tables via MFMA (A-frag shared with QK^T's Q-frag), stored [iw][q] str 66.
// Wave w: nt=w&3 (q tile), mh=w>>2 (j half, 8 m-tiles). PV: A=P[q][j], B=V^T.
// No min-blocks in launch_bounds (r2 lesson).
// ---------------------------------------------------------------------------
__global__ __launch_bounds__(512) void attn_kernel(
    const bf16* __restrict__ QKV, const float* __restrict__ relh,
    const float* __restrict__ relw, bf16* __restrict__ outp)
{
    // LDS layout (60160 B):
    //  [0,5120)      sQb [64][40] u16     (dead after frag loads)
    //  [5120,25600)  sK  [256][40] u16    (dead after QK^T)
    //  [25600,28160) sRH [32][40] u16     (dead after rel MFMA)
    //  [28160,30720) sRW [32][40] u16     (dead after rel MFMA)
    //  [0,33792)     sP  [64][264] u16    OVERLAY (written after all above read)
    //  [33792,50688) sVT [32][264] u16
    //  [50688,59136) tT  [2][16][66] f32  (rel tables, transposed [iw][q])
    //  [59136,59648) wredM [128] f32
    //  [59648,60160) wredS [128] f32
    __shared__ __align__(16) char smem[60160];
    u16*   sQb  = (u16*)(smem);
    u16*   sK   = (u16*)(smem + 5120);
    u16*   sRH  = (u16*)(smem + 25600);
    u16*   sRW  = (u16*)(smem + 28160);
    u16*   sP   = (u16*)(smem);
    u16*   sVT  = (u16*)(smem + 33792);
    float* tT   = (float*)(smem + 50688);
    float* wredM= (float*)(smem + 59136);
    float* wredS= (float*)(smem + 59648);

    const int tid  = threadIdx.x;
    const int bid  = blockIdx.x;
    const int head = bid & 3;
    const int t    = bid >> 2;
    const int n    = t / NBLKS;
    const int blk  = t - n*NBLKS;
    const int bi = blk / 24, bj = blk - bi*24;
    const int row0 = bi*8 - 4, col0 = bj*8 - 4;
    const int ch0 = head*32;
    const int wv = tid >> 6, lane = tid & 63, ln = lane & 15, g = lane >> 4;
    const int nt = wv & 3, mh = wv >> 2;

    // ---- staging ----
    for (int e = tid; e < 1024; e += 512){
        int r = e >> 5, d = e & 31;
        u16 vh = 0, vw = 0;
        if (r < 31){ vh = bits(f2b(relh[r*32+d])); vw = bits(f2b(relw[r*32+d])); }
        sRH[r*40 + d] = vh;
        sRW[r*40 + d] = vw;
    }
    {   // Q: 64 q x 32 d
        int qq = tid >> 3, db = tid & 7;
        size_t P = (size_t)n*HWS + (bi*8 + (qq>>3))*WW + bj*8 + (qq&7);
        *(uint2*)&sQb[qq*40 + db*4] = *(const uint2*)&QKV[P*384 + ch0 + db*4];
    }
    #pragma unroll
    for (int r = 0; r < 4; ++r){   // K rows + V^T scatter
        int e = tid + r*512;
        int wp = e >> 3, db = e & 7;
        int rr = row0 + (wp>>4), cc2 = col0 + (wp&15);
        uint2 kk = {0u,0u}, vv = {0u,0u};
        if (rr>=0 && rr<HH && cc2>=0 && cc2<WW){
            size_t P = (size_t)n*HWS + rr*WW + cc2;
            kk = *(const uint2*)&QKV[P*384 + 128 + ch0 + db*4];
            vv = *(const uint2*)&QKV[P*384 + 256 + ch0 + db*4];
        }
        *(uint2*)&sK[wp*40 + db*4] = kk;
        sVT[(db*4+0)*264 + wp] = (u16)(vv.x & 0xffff);
        sVT[(db*4+1)*264 + wp] = (u16)(vv.x >> 16);
        sVT[(db*4+2)*264 + wp] = (u16)(vv.y & 0xffff);
        sVT[(db*4+3)*264 + wp] = (u16)(vv.y >> 16);
    }
    __syncthreads();

    // ---- QK^T (swapped): accs[i] = C[j-tile mh*8+i][q-tile nt] ----
    const short8 qfrag = *(const short8*)&sQb[(nt*16+ln)*40 + g*8];
    f32x4 accs[8];
    #pragma unroll
    for (int i=0;i<8;i++){
        short8 fk = *(const short8*)&sK[((mh*8+i)*16+ln)*40 + g*8];
        accs[i] = __builtin_amdgcn_mfma_f32_16x16x32_bf16(fk, qfrag, (f32x4){0.f,0.f,0.f,0.f}, 0, 0, 0);
    }

    // ---- rel tables via MFMA: wave (tb=mh, q-tile=nt), A = qfrag ----
    {
        const u16* sRX = mh ? sRW : sRH;
        #pragma unroll
        for (int ntr=0; ntr<2; ++ntr){
            short8 fr = *(const short8*)&sRX[(ntr*16+ln)*40 + g*8];
            f32x4 L = __builtin_amdgcn_mfma_f32_16x16x32_bf16(qfrag, fr, (f32x4){0.f,0.f,0.f,0.f}, 0, 0, 0);
            #pragma unroll
            for (int r2=0;r2<4;r2++){
                int q  = nt*16 + g*4 + r2;
                int rr = ntr*16 + ln;
                int bq = mh ? (q&7) : (q>>3);
                int iw = rr - 15 + bq;
                if (iw >= 0 && iw < 16) tT[mh*1056 + iw*66 + q] = L[r2];
            }
        }
    }
    __syncthreads();

    // ---- bias + mask + max (q = column = nt*16+ln, fixed per lane) ----
    const int qc = nt*16 + ln;
    float tw[4];
    bool cok[4];
    #pragma unroll
    for (int r2=0;r2<4;r2++){
        tw[r2] = tT[1056 + (g*4+r2)*66 + qc];
        int cc2 = col0 + g*4 + r2;
        cok[r2] = (cc2 >= 0 && cc2 < WW);
    }
    float mx = -3.4e38f;
    #pragma unroll
    for (int i=0;i<8;i++){
        int mt = mh*8 + i;
        int rr = row0 + mt;
        bool rok = (rr >= 0 && rr < HH);
        float th = tT[mt*66 + qc];
        #pragma unroll
        for (int r2=0;r2<4;r2++){
            float s = (rok && cok[r2]) ? (accs[i][r2] + th + tw[r2]) : -3.0e38f;
            accs[i][r2] = s;
            mx = fmaxf(mx, s);
        }
    }
    mx = fmaxf(mx, __shfl_xor(mx, 16));
    mx = fmaxf(mx, __shfl_xor(mx, 32));
    if (g == 0) wredM[mh*64 + qc] = mx;
    __syncthreads();
    mx = fmaxf(wredM[qc], wredM[64 + qc]);

    // ---- exp + packed P store + sum ----
    float sm = 0.f;
    #pragma unroll
    for (int i=0;i<8;i++){
        int mt = mh*8 + i;
        float p0 = __expf(accs[i][0]-mx);
        float p1 = __expf(accs[i][1]-mx);
        float p2 = __expf(accs[i][2]-mx);
        float p3 = __expf(accs[i][3]-mx);
        sm += (p0+p1)+(p2+p3);
        u32* dst = (u32*)&sP[qc*264 + mt*16 + g*4];
        dst[0] = pck(p0,p1);
        dst[1] = pck(p2,p3);
    }
    sm += __shfl_xor(sm, 16);
    sm += __shfl_xor(sm, 32);
    if (g == 0) wredS[mh*64 + qc] = sm;
    __syncthreads();

    // ---- PV: wave -> (mtPV = wv>>1, ntPV = wv&1), K = 256 ----
    const int mtPV = wv >> 1, ntPV = wv & 1;
    f32x4 acco = (f32x4){0.f,0.f,0.f,0.f};
    #pragma unroll
    for (int ks=0; ks<8; ++ks){
        short8 fp = *(const short8*)&sP [(mtPV*16+ln)*264 + ks*32 + g*8];
        short8 fv = *(const short8*)&sVT[(ntPV*16+ln)*264 + ks*32 + g*8];
        acco = __builtin_amdgcn_mfma_f32_16x16x32_bf16(fp, fv, acco, 0, 0, 0);
    }
    const int d = ntPV*16 + ln;
    #pragma unroll
    for (int r2=0;r2<4;r2++){
        int qq = mtPV*16 + g*4 + r2;
        float inv = 1.f / (wredS[qq] + wredS[64 + qq]);
        size_t P = (size_t)n*HWS + (bi*8 + (qq>>3))*WW + bj*8 + (qq&7);
        outp[P*CCH + ch0 + d] = f2b(acco[r2] * inv);
    }
}

// ---------------------------------------------------------------------------
extern "C" void kernel_launch(void* const* d_in, const int* in_sizes, int n_in,
                              void* d_out, int out_size, void* d_ws, size_t ws_size,
                              hipStream_t stream)
{
    (void)in_sizes; (void)n_in; (void)out_size; (void)ws_size;
    const float* x      = (const float*)d_in[0];
    const float* w1     = (const float*)d_in[1];
    const float* bn1_g  = (const float*)d_in[2];
    const float* bn1_b  = (const float*)d_in[3];
    const float* bn1_m  = (const float*)d_in[4];
    const float* bn1_v  = (const float*)d_in[5];
    const float* to_q   = (const float*)d_in[6];
    const float* to_kv  = (const float*)d_in[7];
    const float* to_ow  = (const float*)d_in[8];
    const float* to_ob  = (const float*)d_in[9];
    const float* rel_h  = (const float*)d_in[10];
    const float* rel_w  = (const float*)d_in[11];
    const float* w3     = (const float*)d_in[12];
    const float* bn3_g  = (const float*)d_in[13];
    const float* bn3_b  = (const float*)d_in[14];
    const float* bn3_m  = (const float*)d_in[15];
    const float* bn3_v  = (const float*)d_in[16];

    char* ws   = (char*)d_ws;
    bf16* out1 = (bf16*)(ws + 0);              // [P][128]; later reused as out2
    bf16* qkv  = (bf16*)(ws + 18874368);       // [P][384]  q|k|v fused
    bf16* xT   = (bf16*)(ws + 75497472);       // [P][128]
    bf16* wb   = (bf16*)(ws + 94371840);       // weight blob (458752 B)
    bf16* W3p  = wb + 81920;
    bf16* attnout = (bf16*)d_out;              // d_out as scratch until conv3
    bf16* out2    = out1;

    transpose_in<<<4608, 256, 0, stream>>>(x, xT);
    prep_w<<<896, 256, 0, stream>>>(w1, to_q, to_kv, to_ow, w3, wb);

    // conv1 (1x1) + BN1 + ReLU
    gemm_mfma<true,false,true><<<dim3(1152,1), 256, 0, stream>>>(
        xT, wb, out1, 128, 0, bn1_g, bn1_b, bn1_m, bn1_v, nullptr);
    // fused q|k|v (grid.y=3 slabs; Wq,Wk,Wv contiguous at blob+16384)
    gemm_mfma<false,false,false><<<dim3(1152,3), 256, 0, stream>>>(
        out1, wb + 16384, qkv, 384, 0, nullptr,nullptr,nullptr,nullptr,nullptr);

    attn_kernel<<<4608, 512, 0, stream>>>(qkv, rel_h, rel_w, attnout);

    // out projection + bias + ReLU
    gemm_mfma<false,true,true><<<dim3(1152,1), 256, 0, stream>>>(
        attnout, wb + 65536, out2, 128, 0, nullptr,nullptr,nullptr,nullptr, to_ob);

    // conv3 (3x3 convT) + BN3 + residual + ReLU -> NCHW f32 d_out
    conv3_mfma<<<1152, 256, 0, stream>>>(out2, W3p, x, (float*)d_out,
                                         bn3_g, bn3_b, bn3_m, bn3_v);
}